// Round 2
// baseline (28616.483 us; speedup 1.0000x reference)
//
#include <hip/hip_runtime.h>
#include <math.h>

#define Bc 2
#define Sc 2048
#define Dc 1024
#define Hc 16
#define HDc 64
#define FPOLY 4160
#define MHID 2048
#define FFNH 2730
#define GGH 64
#define NTOK 4096
#define NACT 128
#define CHUNK 512
#define NCHUNK 8

// ---------------------------------------------------------------- generic GEMM
// C = act(alpha*op(A)@op(B) + beta*Cin). act applied AFTER beta-add.
// TA: op(A)[m,k] = A[k*lda+m], else A[m*lda+k]. TB: op(B)[k,n] = B[n*ldb+k], else B[k*ldb+n].
template<int TA, int TB>
__global__ __launch_bounds__(256) void gemm_f32(
    const float* __restrict__ A, const float* __restrict__ B,
    const float* __restrict__ Cin, float* __restrict__ C,
    int M, int N, int K, int lda, int ldb, int ldc,
    float alpha, float beta, int act)
{
    __shared__ float As[16][68];
    __shared__ float Bs[16][68];
    const int bm = blockIdx.y * 64;
    const int bn = blockIdx.x * 64;
    const int tid = threadIdx.x;
    const int tx = tid & 15;
    const int ty = tid >> 4;
    float acc[4][4];
#pragma unroll
    for (int i = 0; i < 4; ++i)
#pragma unroll
        for (int j = 0; j < 4; ++j) acc[i][j] = 0.f;
    for (int k0 = 0; k0 < K; k0 += 16) {
#pragma unroll
        for (int l = 0; l < 4; ++l) {
            int i = tid + l * 256;
            int m, kk;
            if (TA) { m = i & 63; kk = i >> 6; } else { kk = i & 15; m = i >> 4; }
            int gm = bm + m, gk = k0 + kk;
            float v = 0.f;
            if (gm < M && gk < K)
                v = TA ? A[(size_t)gk * lda + gm] : A[(size_t)gm * lda + gk];
            As[kk][m] = v;
        }
#pragma unroll
        for (int l = 0; l < 4; ++l) {
            int i = tid + l * 256;
            int n, kk;
            if (TB) { kk = i & 15; n = i >> 4; } else { n = i & 63; kk = i >> 6; }
            int gn = bn + n, gk = k0 + kk;
            float v = 0.f;
            if (gn < N && gk < K)
                v = TB ? B[(size_t)gn * ldb + gk] : B[(size_t)gk * ldb + gn];
            Bs[kk][n] = v;
        }
        __syncthreads();
#pragma unroll
        for (int kk = 0; kk < 16; ++kk) {
            float4 a4 = *(const float4*)&As[kk][ty * 4];
            float4 b4 = *(const float4*)&Bs[kk][tx * 4];
            float av[4] = {a4.x, a4.y, a4.z, a4.w};
            float bv[4] = {b4.x, b4.y, b4.z, b4.w};
#pragma unroll
            for (int i2 = 0; i2 < 4; ++i2)
#pragma unroll
                for (int j2 = 0; j2 < 4; ++j2) acc[i2][j2] += av[i2] * bv[j2];
        }
        __syncthreads();
    }
#pragma unroll
    for (int i2 = 0; i2 < 4; ++i2) {
        int gm = bm + ty * 4 + i2;
        if (gm >= M) continue;
#pragma unroll
        for (int j2 = 0; j2 < 4; ++j2) {
            int gn = bn + tx * 4 + j2;
            if (gn >= N) continue;
            float v = alpha * acc[i2][j2];
            if (beta != 0.f) v += beta * Cin[(size_t)gm * ldc + gn];
            if (act == 1) v = v / (1.f + __expf(-v));   // silu (post-add)
            C[(size_t)gm * ldc + gn] = v;
        }
    }
}

// ---------------------------------------------------------------- small kernels
__global__ __launch_bounds__(256) void rms_rows(
    const float* __restrict__ in, const float* __restrict__ w,
    float* __restrict__ out, int D)
{
    const int row = blockIdx.x;
    const float* r = in + (size_t)row * D;
    float* o = out + (size_t)row * D;
    float s = 0.f;
    for (int i = threadIdx.x; i < D; i += 256) { float v = r[i]; s += v * v; }
    __shared__ float red[256];
    red[threadIdx.x] = s;
    __syncthreads();
    for (int st = 128; st; st >>= 1) {
        if (threadIdx.x < st) red[threadIdx.x] += red[threadIdx.x + st];
        __syncthreads();
    }
    float rs = rsqrtf(red[0] / (float)D + 1e-6f);
    for (int i = threadIdx.x; i < D; i += 256) o[i] = r[i] * rs * w[i];
}

__global__ __launch_bounds__(256) void gamma_kernel(
    const float* __restrict__ gg1, const float* __restrict__ w2,
    float* __restrict__ gamma)
{
    const int tid = threadIdx.x, w = tid >> 6, lane = tid & 63;
    const int t = blockIdx.x * 4 + w;
    float v = gg1[(size_t)t * GGH + lane];
    v = v / (1.f + expf(-v));   // silu
    v *= w2[lane];
#pragma unroll
    for (int off = 32; off; off >>= 1) v += __shfl_xor(v, off);
    if (lane == 0) gamma[t] = 1.f / (1.f + expf(-v));
}

// per-head rmsnorm + rope for ONE tensor (q or k), src row-major (B*S, D)
__global__ __launch_bounds__(256) void snr_one(
    const float* __restrict__ src, const float* __restrict__ w,
    float* __restrict__ dst)
{
    const int tid = threadIdx.x, wv = tid >> 6, lane = tid & 63;
    const int s = blockIdx.x * 4 + wv;
    const int h = blockIdx.y, b = blockIdx.z;
    const size_t row = ((size_t)b * Sc + s) * Dc + h * 64;
    float v = src[row + lane];
    float ss = v * v;
#pragma unroll
    for (int off = 32; off; off >>= 1) ss += __shfl_xor(ss, off);
    v = v * rsqrtf(ss / 64.f + 1e-6f) * w[lane];
    const int j = lane & 31;
    float inv = powf(10000.f, -(float)j / 32.f);
    float ang = (float)s * inv;
    float sn = sinf(ang), cs = cosf(ang);
    float p = __shfl_xor(v, 32);
    float o;
    if (lane < 32) o = v * cs - p * sn;
    else           o = p * sn + v * cs;
    const size_t od = (((size_t)b * Hc + h) * Sc + s) * 64 + lane;
    dst[od] = o;
}

// cumulative-mean of k + gated mix -> q_mem_flat (B,S,D head-major)
__global__ void qmem_kernel(
    const float* __restrict__ qn, const float* __restrict__ kn,
    const float* __restrict__ gamma, float* __restrict__ qmem)
{
    const int bh = blockIdx.x, c = blockIdx.y;
    const int b = bh >> 4, hh = bh & 15;
    const int d = threadIdx.x;
    const size_t base = (size_t)bh * Sc * 64;
    const int s0 = c * 128;
    float a0 = 0, a1 = 0, a2 = 0, a3 = 0;
    for (int s = 0; s < s0; s += 4) {
        a0 += kn[base + (size_t)(s + 0) * 64 + d];
        a1 += kn[base + (size_t)(s + 1) * 64 + d];
        a2 += kn[base + (size_t)(s + 2) * 64 + d];
        a3 += kn[base + (size_t)(s + 3) * 64 + d];
    }
    float run = (a0 + a1) + (a2 + a3);
    for (int s = s0; s < s0 + 128; ++s) {
        run += kn[base + (size_t)s * 64 + d];
        float cm = run / (float)(s + 1);
        float g = gamma[b * Sc + s];
        float qv = qn[base + (size_t)s * 64 + d];
        qmem[((size_t)(b * Sc + s)) * Dc + hh * 64 + d] = g * qv + (1.f - g) * cm;
    }
}

// flash-style causal attention: 64 queries/block, one (b,h) per block
__global__ __launch_bounds__(256) void attn_kernel(
    const float* __restrict__ qn, const float* __restrict__ kn,
    const float* __restrict__ vbuf, float* __restrict__ outp)
{
    const int qb = blockIdx.x * 64;
    const int h = blockIdx.y, b = blockIdx.z;
    const int tid = threadIdx.x;
    const int w = tid >> 6;
    const int lane = tid & 63;
    __shared__ float q_s[64][64];
    __shared__ float kv_s[64][68];
    __shared__ float p_s[64][64];
    const size_t bh = (size_t)b * Hc + h;
    const float* qptr = qn + (bh * Sc + qb) * HDc;
    for (int i = tid; i < 4096; i += 256) {
        int r = i >> 6, d = i & 63;
        q_s[r][d] = qptr[(size_t)r * HDc + d] * 0.125f;   // HD^-0.5
    }
    float m_i[16], l_i[16], o_i[16], corr[16];
#pragma unroll
    for (int r = 0; r < 16; ++r) { m_i[r] = -1e30f; l_i[r] = 0.f; o_i[r] = 0.f; corr[r] = 1.f; }
    __syncthreads();
    const int nchunk = qb / 64 + 1;
    for (int c = 0; c < nchunk; ++c) {
        const int t0 = c * 64;
        const float* kptr = kn + (bh * Sc + t0) * HDc;
        for (int i = tid; i < 1024; i += 256) {
            int r = i >> 4, d4 = (i & 15) * 4;
            float4 kv = *(const float4*)&kptr[(size_t)r * HDc + d4];
            *(float4*)&kv_s[r][d4] = kv;
        }
        __syncthreads();
        float4 kreg[16];
#pragma unroll
        for (int t = 0; t < 16; ++t) kreg[t] = *(const float4*)&kv_s[lane][4 * t];
#pragma unroll 1
        for (int r = 0; r < 16; ++r) {
            const int rg = w * 16 + r;
            const int sq = qb + rg;
            const float4* q4 = (const float4*)&q_s[rg][0];
            float sc = 0.f;
#pragma unroll
            for (int t = 0; t < 16; ++t) {
                float4 qv = q4[t];
                sc += qv.x * kreg[t].x + qv.y * kreg[t].y + qv.z * kreg[t].z + qv.w * kreg[t].w;
            }
            if (t0 + lane > sq) sc = -1e30f;
            float mx = sc;
#pragma unroll
            for (int off = 32; off; off >>= 1) mx = fmaxf(mx, __shfl_xor(mx, off));
            float mnew = fmaxf(m_i[r], mx);
            float p = __expf(sc - mnew);
            float ps = p;
#pragma unroll
            for (int off = 32; off; off >>= 1) ps += __shfl_xor(ps, off);
            corr[r] = __expf(m_i[r] - mnew);
            l_i[r] = l_i[r] * corr[r] + ps;
            m_i[r] = mnew;
            p_s[rg][lane] = p;
        }
        __syncthreads();
        for (int i = tid; i < 1024; i += 256) {   // overwrite kv_s with V tile
            int r = i >> 4, d4 = (i & 15) * 4;
            float4 vv = *(const float4*)&vbuf[((size_t)(b * Sc + t0 + r)) * Dc + h * HDc + d4];
            *(float4*)&kv_s[r][d4] = vv;
        }
        __syncthreads();
#pragma unroll 1
        for (int r = 0; r < 16; ++r) {
            const int rg = w * 16 + r;
            float acc = 0.f;
#pragma unroll
            for (int j = 0; j < 64; j += 4) {
                float4 pv = *(const float4*)&p_s[rg][j];
                acc += pv.x * kv_s[j][lane] + pv.y * kv_s[j + 1][lane]
                     + pv.z * kv_s[j + 2][lane] + pv.w * kv_s[j + 3][lane];
            }
            o_i[r] = o_i[r] * corr[r] + acc;
        }
        __syncthreads();
    }
#pragma unroll
    for (int r = 0; r < 16; ++r) {
        const int rg = w * 16 + r;
        outp[((size_t)(b * Sc + qb + rg)) * Dc + h * HDc + lane] = o_i[r] / l_i[r];
    }
}

__global__ __launch_bounds__(256) void gather_active(
    const float* __restrict__ qmem, const float* __restrict__ vbuf,
    float* __restrict__ xa, float* __restrict__ va)
{
    const int t = blockIdx.x;
    const int b = t >> 6;
    const int s = Sc - 64 + (t & 63);
    const float* qrow = qmem + ((size_t)(b * Sc + s)) * Dc;
    const float* vrow = vbuf + ((size_t)(b * Sc + s)) * Dc;
    for (int i = threadIdx.x; i < Dc; i += 256) {
        xa[(size_t)t * Dc + i] = qrow[i];
        va[(size_t)t * Dc + i] = vrow[i];
    }
}

__global__ void wvec_kernel(const float* __restrict__ gamma,
                            float* __restrict__ wvec, float* __restrict__ wsum)
{
    const int t = threadIdx.x;                  // 128
    const int b = t >> 6, si = t & 63;
    const int s = Sc - 64 + si;
    float v = gamma[b * Sc + s] * powf(0.95f, (float)(Sc - 1 - s));
    wvec[t] = v;
    __shared__ float red[128];
    red[t] = v; __syncthreads();
    for (int st = 64; st; st >>= 1) { if (t < st) red[t] += red[t + st]; __syncthreads(); }
    if (t == 0) wsum[0] = red[0];
}

// phi2 features for `rows` tokens starting at z (rows x 64) -> feat (rows x FPOLY)
__global__ __launch_bounds__(256) void phi2_kernel(
    const float* __restrict__ z, float* __restrict__ feat)
{
    const int f = blockIdx.x * 256 + threadIdx.x;
    const int t = blockIdx.y;
    if (f >= FPOLY) return;
    const float* zr = z + (size_t)t * 64;
    float v;
    if (f < 64) v = zr[f];
    else { int i = (f - 64) >> 6, j = (f - 64) & 63; v = zr[i] * zr[j] * 0.125f; }
    feat[(size_t)t * FPOLY + f] = v;
}

__global__ void silu_kernel(const float* __restrict__ in, float* __restrict__ out, int n)
{
    int i = blockIdx.x * 256 + threadIdx.x;
    if (i < n) { float v = in[i]; out[i] = v / (1.f + expf(-v)); }
}

__global__ void dpred_kernel(const float* __restrict__ pred, const float* __restrict__ va,
                             const float* __restrict__ wvec, const float* __restrict__ wsum,
                             float* __restrict__ dpred)
{
    int i = blockIdx.x * 256 + threadIdx.x;
    if (i < NACT * Dc) {
        int t = i >> 10;
        dpred[i] = 2.f * wvec[t] / (wsum[0] + 1e-8f) * (pred[i] - va[i]);
    }
}

__global__ void dsilu_kernel(const float* __restrict__ dsu, const float* __restrict__ u,
                             float* __restrict__ du, int n)
{
    int i = blockIdx.x * 256 + threadIdx.x;
    if (i < n) {
        float uv = u[i];
        float sg = 1.f / (1.f + expf(-uv));
        du[i] = dsu[i] * sg * (1.f + uv * (1.f - sg));
    }
}

__global__ void dz_kernel(const float* __restrict__ dfeat, const float* __restrict__ za,
                          float* __restrict__ dz)
{
    const int t = blockIdx.x;     // 128
    const int k = threadIdx.x;    // 64
    const float* df = dfeat + (size_t)t * FPOLY;
    const float* z = za + (size_t)t * 64;
    float s1 = 0.f, s2 = 0.f;
    for (int j = 0; j < 64; ++j) {
        float zj = z[j];
        s1 += df[64 + k * 64 + j] * zj;
        s2 += df[64 + j * 64 + k] * zj;
    }
    dz[(size_t)t * 64 + k] = df[k] + 0.125f * (s1 + s2);
}

__global__ void add_diag_kernel(float* __restrict__ F)
{
    int i = threadIdx.x;   // 128
    F[i * 128 + i] += 3.4445f;
}

__global__ void zero_kernel(float* p, int n)
{
    int i = blockIdx.x * blockDim.x + threadIdx.x;
    if (i < n) p[i] = 0.f;
}

__global__ void dot_reduce(const float* __restrict__ a, const float* __restrict__ b,
                           int n, float* __restrict__ out)
{
    float s = 0.f;
    for (int i = blockIdx.x * blockDim.x + threadIdx.x; i < n; i += gridDim.x * blockDim.x)
        s += a[i] * b[i];
    __shared__ float red[256];
    const int t = threadIdx.x;
    red[t] = s; __syncthreads();
    for (int st = 128; st; st >>= 1) { if (t < st) red[t] += red[t + st]; __syncthreads(); }
    if (t == 0) atomicAdd(out, red[0]);
}

__global__ void scale_kernel(const float* __restrict__ src, float* __restrict__ dst,
                             int n, const float* __restrict__ ss)
{
    int i = blockIdx.x * 256 + threadIdx.x;
    if (i < n) dst[i] = src[i] / (sqrtf(ss[0]) + 1e-7f);
}

__global__ void axpy_gate_kernel(float* __restrict__ x2, const float* __restrict__ mem,
                                 const float* __restrict__ mg, int n)
{
    int i = blockIdx.x * 256 + threadIdx.x;
    if (i < n) {
        float g = 1.f / (1.f + expf(-mg[0]));
        x2[i] += g * mem[i];
    }
}

__global__ void mul_kernel(float* __restrict__ a, const float* __restrict__ b, int n)
{
    int i = blockIdx.x * 256 + threadIdx.x;
    if (i < n) a[i] *= b[i];
}

// ---------------------------------------------------------------- launch
extern "C" void kernel_launch(void* const* d_in, const int* in_sizes, int n_in,
                              void* d_out, int out_size, void* d_ws, size_t ws_size,
                              hipStream_t stream)
{
    const float* x     = (const float*)d_in[0];
    const float* n1w   = (const float*)d_in[1];
    const float* n2w   = (const float*)d_in[2];
    const float* qkvw  = (const float*)d_in[3];
    const float* qnw   = (const float*)d_in[4];
    const float* knw   = (const float*)d_in[5];
    const float* gw1   = (const float*)d_in[6];
    const float* gw2   = (const float*)d_in[7];
    const float* mwk   = (const float*)d_in[8];
    const float* mw1   = (const float*)d_in[9];
    const float* mw2   = (const float*)d_in[10];
    const float* mgate = (const float*)d_in[11];
    const float* wow   = (const float*)d_in[12];
    const float* fw1   = (const float*)d_in[13];
    const float* fw2   = (const float*)d_in[14];
    const float* fw3   = (const float*)d_in[15];
    float* outp = (float*)d_out;

    float* Wf = (float*)d_ws;
    size_t off = 0;
    auto take = [&](size_t n) { float* p = Wf + off; off += (n + 63) & ~(size_t)63; return p; };

    // arena ~135 MB total (ws-safe). Liveness-based overlays noted inline.
    float* qt    = take((size_t)NTOK * Dc);   // q/k temp; dead after snr -> featC/ff1C overlay
    float* qn    = take((size_t)NTOK * Dc);   // dead after attn -> ff3C overlay
    float* kn    = take((size_t)NTOK * Dc);   // dead after attn
    float* vbuf  = take((size_t)NTOK * Dc);   // dead after attn+gather
    float* qmem  = take((size_t)NTOK * Dc);   // dead after zf+gather
    float* attn  = take((size_t)NTOK * Dc);   // dead after x2 gemm -> h2 overlay
    float* hbuf  = take((size_t)NTOK * Dc);   // dead after qkv/gg1 gemms -> x2 overlay
    float* zf    = take((size_t)NTOK * HDc);
    float* gamma = take(NTOK);
    float* gg1   = take((size_t)NTOK * GGH);
    float* wvec  = take(NACT);
    float* scal  = take(64);                  // [0]=Wsum, [1]=NS norm^2
    float* xa    = take((size_t)NACT * Dc);
    float* va    = take((size_t)NACT * Dc);
    float* za    = take((size_t)NACT * HDc);
    float* featA = take((size_t)NACT * FPOLY);
    float* ua    = take((size_t)NACT * MHID);
    float* sua   = take((size_t)NACT * MHID);
    float* preda = take((size_t)NACT * Dc);
    float* dpreda= take((size_t)NACT * Dc);
    float* dsua  = take((size_t)NACT * MHID);
    float* dua   = take((size_t)NACT * MHID);
    float* dfeata= take((size_t)NACT * FPOLY);
    float* dza   = take((size_t)NACT * HDc);
    float* Sb    = take(128 * 128);
    float* Gb    = take(128 * 128);
    float* Mb    = take(128 * 128);
    float* Fb    = take(128 * 128);
    float* Tb    = take((size_t)128 * MHID);
    float* PTa   = take((size_t)128 * MHID);  // shared NS ping buffer
    float* PT1   = take((size_t)128 * MHID);  // NS results (persist into chunk loop)
    float* PT2   = take((size_t)128 * Dc);
    float* PT3   = take((size_t)128 * HDc);
    float* wku   = take((size_t)Dc * HDc);
    float* t1C   = take((size_t)CHUNK * MHID);
    float* tBC   = take((size_t)CHUNK * NACT);
    float* memoC = take((size_t)CHUNK * Dc);
    // overlays (liveness-verified)
    float* featC = qt;       // CHUNK*FPOLY = 2.13M floats <= 4.19M
    float* ff1C  = qt;       // CHUNK*FFNH  = 1.40M floats
    float* ff3C  = qn;       // CHUNK*FFNH
    float* x2    = hbuf;
    float* h2    = attn;

    auto gemm = [&](int TA, int TB, const float* A, const float* B, const float* Cin, float* C,
                    int M, int N, int K, int lda, int ldb, int ldc,
                    float alpha, float beta, int act) {
        dim3 grid((N + 63) / 64, (M + 63) / 64);
        if (!TA && !TB)      gemm_f32<0, 0><<<grid, 256, 0, stream>>>(A, B, Cin, C, M, N, K, lda, ldb, ldc, alpha, beta, act);
        else if (!TA && TB)  gemm_f32<0, 1><<<grid, 256, 0, stream>>>(A, B, Cin, C, M, N, K, lda, ldb, ldc, alpha, beta, act);
        else if (TA && !TB)  gemm_f32<1, 0><<<grid, 256, 0, stream>>>(A, B, Cin, C, M, N, K, lda, ldb, ldc, alpha, beta, act);
        else                 gemm_f32<1, 1><<<grid, 256, 0, stream>>>(A, B, Cin, C, M, N, K, lda, ldb, ldc, alpha, beta, act);
    };

    // 1. h = rmsnorm(x)
    rms_rows<<<NTOK, 256, 0, stream>>>(x, n1w, hbuf, Dc);
    // 2. q/k/v + gamma (split GEMMs; qt reused for q then k)
    gemm(0, 0, hbuf, qkvw + 0,    nullptr, qt,   NTOK, Dc, Dc, Dc, 3 * Dc, Dc, 1.f, 0.f, 0);
    snr_one<<<dim3(Sc / 4, Hc, Bc), 256, 0, stream>>>(qt, qnw, qn);
    gemm(0, 0, hbuf, qkvw + 1024, nullptr, qt,   NTOK, Dc, Dc, Dc, 3 * Dc, Dc, 1.f, 0.f, 0);
    snr_one<<<dim3(Sc / 4, Hc, Bc), 256, 0, stream>>>(qt, knw, kn);
    gemm(0, 0, hbuf, qkvw + 2048, nullptr, vbuf, NTOK, Dc, Dc, Dc, 3 * Dc, Dc, 1.f, 0.f, 0);
    gemm(0, 0, hbuf, gw1, nullptr, gg1, NTOK, GGH, Dc, Dc, GGH, GGH, 1.f, 0.f, 0);
    gamma_kernel<<<NTOK / 4, 256, 0, stream>>>(gg1, gw2, gamma);
    // 3. q_mem (cumulative mean mix)
    qmem_kernel<<<dim3(Bc * Hc, 16), 64, 0, stream>>>(qn, kn, gamma, qmem);
    // 4. causal attention
    attn_kernel<<<dim3(Sc / 64, Hc, Bc), 256, 0, stream>>>(qn, kn, vbuf, attn);
    // 5. grads on 128 active tokens
    gather_active<<<NACT, 256, 0, stream>>>(qmem, vbuf, xa, va);
    wvec_kernel<<<1, 128, 0, stream>>>(gamma, wvec, scal);
    gemm(0, 0, xa, mwk, nullptr, za, NACT, HDc, Dc, Dc, HDc, HDc, 1.f, 0.f, 0);
    phi2_kernel<<<dim3((FPOLY + 255) / 256, NACT), 256, 0, stream>>>(za, featA);
    gemm(0, 0, featA, mw1, nullptr, ua, NACT, MHID, FPOLY, FPOLY, MHID, MHID, 1.f, 0.f, 0);
    silu_kernel<<<(NACT * MHID + 255) / 256, 256, 0, stream>>>(ua, sua, NACT * MHID);
    gemm(0, 0, sua, mw2, nullptr, preda, NACT, Dc, MHID, MHID, Dc, Dc, 1.f, 0.f, 0);
    dpred_kernel<<<(NACT * Dc + 255) / 256, 256, 0, stream>>>(preda, va, wvec, scal, dpreda);
    gemm(0, 1, dpreda, mw2, nullptr, dsua, NACT, MHID, Dc, Dc, Dc, MHID, 1.f, 0.f, 0);
    dsilu_kernel<<<(NACT * MHID + 255) / 256, 256, 0, stream>>>(dsua, ua, dua, NACT * MHID);
    gemm(0, 1, dua, mw1, nullptr, dfeata, NACT, FPOLY, MHID, MHID, MHID, FPOLY, 1.f, 0.f, 0);
    dz_kernel<<<NACT, 64, 0, stream>>>(dfeata, za, dza);

    // low-rank Newton-Schulz: X_t = P_t Q (X0 = G^T/||G||), PT' = F^T PT,
    // F = aI + bM + cM^2, M = (QQ^T)(P^T P). Result always lands in `outb` (odd #iters).
    auto ns_lowrank = [&](const float* Q, int nq, const float* PTraw, int np, float* outb) {
        gemm(0, 1, Q, Q, nullptr, Sb, 128, 128, nq, nq, nq, 128, 1.f, 0.f, 0);
        gemm(0, 0, Sb, PTraw, nullptr, Tb, 128, np, 128, 128, np, np, 1.f, 0.f, 0);
        zero_kernel<<<1, 64, 0, stream>>>(scal + 1, 1);
        dot_reduce<<<64, 256, 0, stream>>>(Tb, PTraw, 128 * np, scal + 1);   // ||G||_F^2
        scale_kernel<<<(128 * np + 255) / 256, 256, 0, stream>>>(PTraw, PTa, 128 * np, scal + 1);
        float* cur = PTa; float* alt = outb;
        for (int it = 0; it < 5; ++it) {
            gemm(0, 1, cur, cur, nullptr, Gb, 128, 128, np, np, np, 128, 1.f, 0.f, 0);   // P^T P
            gemm(0, 0, Sb, Gb, nullptr, Mb, 128, 128, 128, 128, 128, 128, 1.f, 0.f, 0); // M
            gemm(0, 0, Mb, Mb, Mb, Fb, 128, 128, 128, 128, 128, 128, 2.0315f, -4.775f, 0); // cM^2+bM
            add_diag_kernel<<<1, 128, 0, stream>>>(Fb);                                  // +aI
            gemm(1, 0, Fb, cur, nullptr, alt, 128, np, 128, 128, np, np, 1.f, 0.f, 0);   // F^T PT
            float* t = cur; cur = alt; alt = t;
        }
    };

    ns_lowrank(featA, FPOLY, dua, MHID, PT1);
    ns_lowrank(sua, MHID, dpreda, Dc, PT2);
    ns_lowrank(xa, Dc, dza, HDc, PT3);
    // wku = 0.999*mwk - 0.01*xa^T@PT3  (materialized: tiny)
    gemm(1, 0, xa, PT3, mwk, wku, Dc, HDc, 128, Dc, HDc, HDc, -0.01f, 0.999f, 0);

    // 6. x2 = x + attn@wo  (memory-out added chunkwise below)
    gemm(0, 0, attn, wow, x, x2, NTOK, Dc, Dc, Dc, Dc, Dc, 1.f, 1.f, 0);
    // 7. memory forward with updated weights (low-rank w1u/w2u, chunked)
    gemm(0, 0, qmem, wku, nullptr, zf, NTOK, HDc, Dc, Dc, HDc, HDc, 1.f, 0.f, 0);
    for (int c = 0; c < NCHUNK; ++c) {
        const int R = c * CHUNK;
        phi2_kernel<<<dim3((FPOLY + 255) / 256, CHUNK), 256, 0, stream>>>(zf + (size_t)R * HDc, featC);
        // u = 0.999*feat@mw1 - 0.01*(feat@featA^T)@PT1 ; t1 = silu(u)
        gemm(0, 0, featC, mw1, nullptr, t1C, CHUNK, MHID, FPOLY, FPOLY, MHID, MHID, 0.999f, 0.f, 0);
        gemm(0, 1, featC, featA, nullptr, tBC, CHUNK, NACT, FPOLY, FPOLY, FPOLY, NACT, 1.f, 0.f, 0);
        gemm(0, 0, tBC, PT1, t1C, t1C, CHUNK, MHID, NACT, NACT, MHID, MHID, -0.01f, 1.f, 1);
        // mem = 0.999*su@mw2 - 0.01*(su@sua^T)@PT2
        gemm(0, 0, t1C, mw2, nullptr, memoC, CHUNK, Dc, MHID, MHID, Dc, Dc, 0.999f, 0.f, 0);
        gemm(0, 1, t1C, sua, nullptr, tBC, CHUNK, NACT, MHID, MHID, MHID, NACT, 1.f, 0.f, 0);
        gemm(0, 0, tBC, PT2, memoC, memoC, CHUNK, Dc, NACT, NACT, Dc, Dc, -0.01f, 1.f, 0);
        axpy_gate_kernel<<<(CHUNK * Dc + 255) / 256, 256, 0, stream>>>(
            x2 + (size_t)R * Dc, memoC, mgate, CHUNK * Dc);
    }
    // 8. FFN (swiglu), chunked
    rms_rows<<<NTOK, 256, 0, stream>>>(x2, n2w, h2, Dc);
    for (int c = 0; c < NCHUNK; ++c) {
        const int R = c * CHUNK;
        gemm(0, 0, h2 + (size_t)R * Dc, fw1, nullptr, ff1C, CHUNK, FFNH, Dc, Dc, FFNH, FFNH, 1.f, 0.f, 1);
        gemm(0, 0, h2 + (size_t)R * Dc, fw3, nullptr, ff3C, CHUNK, FFNH, Dc, Dc, FFNH, FFNH, 1.f, 0.f, 0);
        mul_kernel<<<(CHUNK * FFNH + 255) / 256, 256, 0, stream>>>(ff1C, ff3C, CHUNK * FFNH);
        gemm(0, 0, ff1C, fw2, x2 + (size_t)R * Dc, outp + (size_t)R * Dc,
             CHUNK, Dc, FFNH, FFNH, Dc, Dc, 1.f, 1.f, 0);
    }
}

// Round 3
// 7586.633 us; speedup vs baseline: 3.7720x; 3.7720x over previous
//
#include <hip/hip_runtime.h>
#include <math.h>

#define Bc 2
#define Sc 2048
#define Dc 1024
#define Hc 16
#define HDc 64
#define FPOLY 4160
#define MHID 2048
#define FFNH 2730
#define FFNHP 2752   // FFNH padded to mult of 32 (K pad, zero-filled)
#define FFNHR 2816   // FFNH padded to mult of 128 (N rows allocated)
#define GGH 64
#define NTOK 4096
#define NACT 128
#define MCH 2048     // memory-forward M chunk

typedef __bf16 bf16;
typedef __attribute__((ext_vector_type(8))) __bf16 bf16x8;
typedef __attribute__((ext_vector_type(4))) float f32x4;

#define AS1 __attribute__((address_space(1)))
#define AS3 __attribute__((address_space(3)))

__device__ __forceinline__ void gload16(const void* g, void* l) {
    __builtin_amdgcn_global_load_lds((AS1 const void*)g, (AS3 void*)l, 16, 0, 0);
}

// ---------------------------------------------------------------- bf16 MFMA GEMM
// C = act(alpha*[sptr]*A@Bt^T + beta*Cin).  A:(M,K) bf16 row-major, Bt:(N,K) bf16
// row-major (i.e. B^T). K%32==0, M%128==0. N arbitrary (col-masked stores).
// Bt must have ceil(N/128)*128 rows ALLOCATED (pad rows may be garbage).
template<int OUTBF, int CINBF>
__global__ __launch_bounds__(256) void gemm_bt(
    const bf16* __restrict__ A, const bf16* __restrict__ Bt,
    const void* __restrict__ Cin, void* __restrict__ Cout,
    int M, int N, int K, int ldc,
    float alpha, float beta, int act, const float* __restrict__ sptr)
{
    __shared__ bf16 As[128 * 32];
    __shared__ bf16 Bs[128 * 32];
    const int tid = threadIdx.x;
    const int w = tid >> 6, lane = tid & 63;
    const int bm = blockIdx.y * 128, bn = blockIdx.x * 128;
    const int wm = (w >> 1) * 64, wn = (w & 1) * 64;
    f32x4 acc[4][4];
#pragma unroll
    for (int i = 0; i < 4; ++i)
#pragma unroll
        for (int j = 0; j < 4; ++j) { acc[i][j][0] = 0.f; acc[i][j][1] = 0.f; acc[i][j][2] = 0.f; acc[i][j][3] = 0.f; }
    // staging geometry: idx in [0,512): row=idx>>2, 16B chunk slot=idx&3.
    // swizzle: LDS slot c holds global chunk g = c ^ ((row>>1)&3)
    const int idx0 = tid, idx1 = tid + 256;
    const int r0 = idx0 >> 2, r1 = idx1 >> 2;
    const int g0 = ((idx0 & 3) ^ ((r0 >> 1) & 3)) * 8;
    const int g1 = ((idx1 & 3) ^ ((r1 >> 1) & 3)) * 8;
    char* ldsA0 = (char*)As + w * 1024;
    char* ldsB0 = (char*)Bs + w * 1024;
    const int lrow = lane & 15;
    const int q = lane >> 4;
    // fragment LDS element offsets (row*32 + swizzled-slot*8)
    int aoff[4], boff[4];
#pragma unroll
    for (int t = 0; t < 4; ++t) {
        int ar = wm + t * 16 + lrow;
        aoff[t] = ar * 32 + ((q ^ ((ar >> 1) & 3)) * 8);
        int br = wn + t * 16 + lrow;
        boff[t] = br * 32 + ((q ^ ((br >> 1) & 3)) * 8);
    }
    const bf16* Arow0 = A + (size_t)(bm + r0) * K + g0;
    const bf16* Arow1 = A + (size_t)(bm + r1) * K + g1;
    const bf16* Brow0 = Bt + (size_t)(bn + r0) * K + g0;
    const bf16* Brow1 = Bt + (size_t)(bn + r1) * K + g1;
    for (int k0 = 0; k0 < K; k0 += 32) {
        gload16(Arow0 + k0, ldsA0);
        gload16(Arow1 + k0, ldsA0 + 4096);
        gload16(Brow0 + k0, ldsB0);
        gload16(Brow1 + k0, ldsB0 + 4096);
        __syncthreads();
        bf16x8 af[4], bfr[4];
#pragma unroll
        for (int t = 0; t < 4; ++t) af[t] = *(const bf16x8*)&As[aoff[t]];
#pragma unroll
        for (int t = 0; t < 4; ++t) bfr[t] = *(const bf16x8*)&Bs[boff[t]];
#pragma unroll
        for (int mt = 0; mt < 4; ++mt)
#pragma unroll
            for (int nt = 0; nt < 4; ++nt)
                acc[mt][nt] = __builtin_amdgcn_mfma_f32_16x16x32_bf16(af[mt], bfr[nt], acc[mt][nt], 0, 0, 0);
        __syncthreads();
    }
    const float amul = alpha * (sptr ? *sptr : 1.f);
#pragma unroll
    for (int nt = 0; nt < 4; ++nt) {
        const int col = bn + wn + nt * 16 + lrow;
        if (col >= N) continue;
#pragma unroll
        for (int mt = 0; mt < 4; ++mt) {
            const int rbase = bm + wm + mt * 16 + q * 4;
#pragma unroll
            for (int r = 0; r < 4; ++r) {
                const size_t o = (size_t)(rbase + r) * ldc + col;
                float v = amul * acc[mt][nt][r];
                if (beta != 0.f)
                    v += beta * (CINBF ? (float)((const bf16*)Cin)[o] : ((const float*)Cin)[o]);
                if (act == 1) v = v / (1.f + __expf(-v));
                if (OUTBF) ((bf16*)Cout)[o] = (bf16)v;
                else       ((float*)Cout)[o] = v;
            }
        }
    }
}

// ---------------------------------------------------------------- fp32 GEMM (small/precision paths)
template<int TA, int TB>
__global__ __launch_bounds__(256) void gemm_f32(
    const float* __restrict__ A, const float* __restrict__ B,
    const float* __restrict__ Cin, float* __restrict__ C,
    int M, int N, int K, int lda, int ldb, int ldc,
    float alpha, float beta, int act)
{
    __shared__ float As[16][68];
    __shared__ float Bs[16][68];
    const int bm = blockIdx.y * 64;
    const int bn = blockIdx.x * 64;
    const int tid = threadIdx.x;
    const int tx = tid & 15;
    const int ty = tid >> 4;
    float acc[4][4];
#pragma unroll
    for (int i = 0; i < 4; ++i)
#pragma unroll
        for (int j = 0; j < 4; ++j) acc[i][j] = 0.f;
    for (int k0 = 0; k0 < K; k0 += 16) {
#pragma unroll
        for (int l = 0; l < 4; ++l) {
            int i = tid + l * 256;
            int m, kk;
            if (TA) { m = i & 63; kk = i >> 6; } else { kk = i & 15; m = i >> 4; }
            int gm = bm + m, gk = k0 + kk;
            float v = 0.f;
            if (gm < M && gk < K)
                v = TA ? A[(size_t)gk * lda + gm] : A[(size_t)gm * lda + gk];
            As[kk][m] = v;
        }
#pragma unroll
        for (int l = 0; l < 4; ++l) {
            int i = tid + l * 256;
            int n, kk;
            if (TB) { kk = i & 15; n = i >> 4; } else { n = i & 63; kk = i >> 6; }
            int gn = bn + n, gk = k0 + kk;
            float v = 0.f;
            if (gn < N && gk < K)
                v = TB ? B[(size_t)gn * ldb + gk] : B[(size_t)gk * ldb + gn];
            Bs[kk][n] = v;
        }
        __syncthreads();
#pragma unroll
        for (int kk = 0; kk < 16; ++kk) {
            float4 a4 = *(const float4*)&As[kk][ty * 4];
            float4 b4 = *(const float4*)&Bs[kk][tx * 4];
            float av[4] = {a4.x, a4.y, a4.z, a4.w};
            float bv[4] = {b4.x, b4.y, b4.z, b4.w};
#pragma unroll
            for (int i2 = 0; i2 < 4; ++i2)
#pragma unroll
                for (int j2 = 0; j2 < 4; ++j2) acc[i2][j2] += av[i2] * bv[j2];
        }
        __syncthreads();
    }
#pragma unroll
    for (int i2 = 0; i2 < 4; ++i2) {
        int gm = bm + ty * 4 + i2;
        if (gm >= M) continue;
#pragma unroll
        for (int j2 = 0; j2 < 4; ++j2) {
            int gn = bn + tx * 4 + j2;
            if (gn >= N) continue;
            float v = alpha * acc[i2][j2];
            if (beta != 0.f) v += beta * Cin[(size_t)gm * ldc + gn];
            if (act == 1) v = v / (1.f + __expf(-v));
            C[(size_t)gm * ldc + gn] = v;
        }
    }
}

// ---------------------------------------------------------------- converts
// W (K,N) fp32 -> Wt (N, Kpad) bf16, zero-fill k in [K,Kpad)
__global__ __launch_bounds__(256) void tconv_kernel(
    const float* __restrict__ W, bf16* __restrict__ Wt, int K, int N, int Kpad)
{
    __shared__ float t[32][33];
    const int k0 = blockIdx.x * 32, n0 = blockIdx.y * 32;
    const int tx = threadIdx.x & 31, ty = threadIdx.x >> 5;
#pragma unroll
    for (int r = 0; r < 4; ++r) {
        int gk = k0 + ty + r * 8, gn = n0 + tx;
        t[ty + r * 8][tx] = (gk < K && gn < N) ? W[(size_t)gk * N + gn] : 0.f;
    }
    __syncthreads();
#pragma unroll
    for (int r = 0; r < 4; ++r) {
        int gn = n0 + ty + r * 8, gk = k0 + tx;
        if (gn < N && gk < Kpad) Wt[(size_t)gn * Kpad + gk] = (bf16)t[tx][ty + r * 8];
    }
}

__global__ void cvt_kernel(const float* __restrict__ in, bf16* __restrict__ out, int n)
{
    for (int i = blockIdx.x * 256 + threadIdx.x; i < n; i += gridDim.x * 256)
        out[i] = (bf16)in[i];
}

// ---------------------------------------------------------------- small kernels
__global__ __launch_bounds__(256) void rms_rows(
    const float* __restrict__ in, const float* __restrict__ w,
    bf16* __restrict__ out, int D)
{
    const int row = blockIdx.x;
    const float* r = in + (size_t)row * D;
    bf16* o = out + (size_t)row * D;
    float s = 0.f;
    for (int i = threadIdx.x; i < D; i += 256) { float v = r[i]; s += v * v; }
    __shared__ float red[256];
    red[threadIdx.x] = s;
    __syncthreads();
    for (int st = 128; st; st >>= 1) {
        if (threadIdx.x < st) red[threadIdx.x] += red[threadIdx.x + st];
        __syncthreads();
    }
    float rs = rsqrtf(red[0] / (float)D + 1e-6f);
    for (int i = threadIdx.x; i < D; i += 256) o[i] = (bf16)(r[i] * rs * w[i]);
}

__global__ __launch_bounds__(256) void gamma_kernel(
    const float* __restrict__ gg1, const float* __restrict__ w2,
    float* __restrict__ gamma)
{
    const int tid = threadIdx.x, w = tid >> 6, lane = tid & 63;
    const int t = blockIdx.x * 4 + w;
    float v = gg1[(size_t)t * GGH + lane];
    v = v / (1.f + expf(-v));
    v *= w2[lane];
#pragma unroll
    for (int off = 32; off; off >>= 1) v += __shfl_xor(v, off);
    if (lane == 0) gamma[t] = 1.f / (1.f + expf(-v));
}

// per-head rmsnorm + rope (bf16 in/out)
__global__ __launch_bounds__(256) void snr_one(
    const bf16* __restrict__ src, const float* __restrict__ w,
    bf16* __restrict__ dst)
{
    const int tid = threadIdx.x, wv = tid >> 6, lane = tid & 63;
    const int s = blockIdx.x * 4 + wv;
    const int h = blockIdx.y, b = blockIdx.z;
    const size_t row = ((size_t)b * Sc + s) * Dc + h * 64;
    float v = (float)src[row + lane];
    float ss = v * v;
#pragma unroll
    for (int off = 32; off; off >>= 1) ss += __shfl_xor(ss, off);
    v = v * rsqrtf(ss / 64.f + 1e-6f) * w[lane];
    const int j = lane & 31;
    float inv = powf(10000.f, -(float)j / 32.f);
    float ang = (float)s * inv;
    float sn = sinf(ang), cs = cosf(ang);
    float p = __shfl_xor(v, 32);
    float o;
    if (lane < 32) o = v * cs - p * sn;
    else           o = p * sn + v * cs;
    const size_t od = (((size_t)b * Hc + h) * Sc + s) * 64 + lane;
    dst[od] = (bf16)o;
}

__global__ void qmem_kernel(
    const bf16* __restrict__ qn, const bf16* __restrict__ kn,
    const float* __restrict__ gamma, float* __restrict__ qmem)
{
    const int bh = blockIdx.x, c = blockIdx.y;
    const int b = bh >> 4, hh = bh & 15;
    const int d = threadIdx.x;
    const size_t base = (size_t)bh * Sc * 64;
    const int s0 = c * 128;
    float a0 = 0, a1 = 0, a2 = 0, a3 = 0;
    for (int s = 0; s < s0; s += 4) {
        a0 += (float)kn[base + (size_t)(s + 0) * 64 + d];
        a1 += (float)kn[base + (size_t)(s + 1) * 64 + d];
        a2 += (float)kn[base + (size_t)(s + 2) * 64 + d];
        a3 += (float)kn[base + (size_t)(s + 3) * 64 + d];
    }
    float run = (a0 + a1) + (a2 + a3);
    for (int s = s0; s < s0 + 128; ++s) {
        run += (float)kn[base + (size_t)s * 64 + d];
        float cm = run / (float)(s + 1);
        float g = gamma[b * Sc + s];
        float qv = (float)qn[base + (size_t)s * 64 + d];
        qmem[((size_t)(b * Sc + s)) * Dc + hh * 64 + d] = g * qv + (1.f - g) * cm;
    }
}

// flash-style causal attention (fp32 compute, bf16 I/O)
__global__ __launch_bounds__(256) void attn_kernel(
    const bf16* __restrict__ qn, const bf16* __restrict__ kn,
    const bf16* __restrict__ vbuf, bf16* __restrict__ outp)
{
    const int qb = blockIdx.x * 64;
    const int h = blockIdx.y, b = blockIdx.z;
    const int tid = threadIdx.x;
    const int w = tid >> 6;
    const int lane = tid & 63;
    __shared__ float q_s[64][64];
    __shared__ float kv_s[64][68];
    __shared__ float p_s[64][64];
    const size_t bh = (size_t)b * Hc + h;
    const bf16* qptr = qn + (bh * Sc + qb) * HDc;
    for (int i = tid; i < 4096; i += 256) {
        int r = i >> 6, d = i & 63;
        q_s[r][d] = (float)qptr[(size_t)r * HDc + d] * 0.125f;
    }
    float m_i[16], l_i[16], o_i[16], corr[16];
#pragma unroll
    for (int r = 0; r < 16; ++r) { m_i[r] = -1e30f; l_i[r] = 0.f; o_i[r] = 0.f; corr[r] = 1.f; }
    __syncthreads();
    const int nchunk = qb / 64 + 1;
    for (int c = 0; c < nchunk; ++c) {
        const int t0 = c * 64;
        const bf16* kptr = kn + (bh * Sc + t0) * HDc;
        for (int i = tid; i < 4096; i += 256) {
            int r = i >> 6, d = i & 63;
            kv_s[r][d] = (float)kptr[(size_t)r * HDc + d];
        }
        __syncthreads();
        float4 kreg[16];
#pragma unroll
        for (int t = 0; t < 16; ++t) kreg[t] = *(const float4*)&kv_s[lane][4 * t];
#pragma unroll 1
        for (int r = 0; r < 16; ++r) {
            const int rg = w * 16 + r;
            const int sq = qb + rg;
            const float4* q4 = (const float4*)&q_s[rg][0];
            float sc = 0.f;
#pragma unroll
            for (int t = 0; t < 16; ++t) {
                float4 qv = q4[t];
                sc += qv.x * kreg[t].x + qv.y * kreg[t].y + qv.z * kreg[t].z + qv.w * kreg[t].w;
            }
            if (t0 + lane > sq) sc = -1e30f;
            float mx = sc;
#pragma unroll
            for (int off = 32; off; off >>= 1) mx = fmaxf(mx, __shfl_xor(mx, off));
            float mnew = fmaxf(m_i[r], mx);
            float p = __expf(sc - mnew);
            float ps = p;
#pragma unroll
            for (int off = 32; off; off >>= 1) ps += __shfl_xor(ps, off);
            corr[r] = __expf(m_i[r] - mnew);
            l_i[r] = l_i[r] * corr[r] + ps;
            m_i[r] = mnew;
            p_s[rg][lane] = p;
        }
        __syncthreads();
        for (int i = tid; i < 4096; i += 256) {
            int r = i >> 6, d = i & 63;
            kv_s[r][d] = (float)vbuf[((size_t)(b * Sc + t0 + r)) * Dc + h * HDc + d];
        }
        __syncthreads();
#pragma unroll 1
        for (int r = 0; r < 16; ++r) {
            const int rg = w * 16 + r;
            float acc = 0.f;
#pragma unroll
            for (int j = 0; j < 64; j += 4) {
                float4 pv = *(const float4*)&p_s[rg][j];
                acc += pv.x * kv_s[j][lane] + pv.y * kv_s[j + 1][lane]
                     + pv.z * kv_s[j + 2][lane] + pv.w * kv_s[j + 3][lane];
            }
            o_i[r] = o_i[r] * corr[r] + acc;
        }
        __syncthreads();
    }
#pragma unroll
    for (int r = 0; r < 16; ++r) {
        const int rg = w * 16 + r;
        outp[((size_t)(b * Sc + qb + rg)) * Dc + h * HDc + lane] = (bf16)(o_i[r] / l_i[r]);
    }
}

__global__ __launch_bounds__(256) void gather_active(
    const float* __restrict__ qmem, const bf16* __restrict__ vbuf,
    float* __restrict__ xa, float* __restrict__ va)
{
    const int t = blockIdx.x;
    const int b = t >> 6;
    const int s = Sc - 64 + (t & 63);
    const float* qrow = qmem + ((size_t)(b * Sc + s)) * Dc;
    const bf16* vrow = vbuf + ((size_t)(b * Sc + s)) * Dc;
    for (int i = threadIdx.x; i < Dc; i += 256) {
        xa[(size_t)t * Dc + i] = qrow[i];
        va[(size_t)t * Dc + i] = (float)vrow[i];
    }
}

__global__ void wvec_kernel(const float* __restrict__ gamma,
                            float* __restrict__ wvec, float* __restrict__ wsum)
{
    const int t = threadIdx.x;
    const int b = t >> 6, si = t & 63;
    const int s = Sc - 64 + si;
    float v = gamma[b * Sc + s] * powf(0.95f, (float)(Sc - 1 - s));
    wvec[t] = v;
    __shared__ float red[128];
    red[t] = v; __syncthreads();
    for (int st = 64; st; st >>= 1) { if (t < st) red[t] += red[t + st]; __syncthreads(); }
    if (t == 0) wsum[0] = red[0];
}

__global__ __launch_bounds__(256) void phi2_f32(
    const float* __restrict__ z, float* __restrict__ feat)
{
    const int f = blockIdx.x * 256 + threadIdx.x;
    const int t = blockIdx.y;
    if (f >= FPOLY) return;
    const float* zr = z + (size_t)t * 64;
    float v;
    if (f < 64) v = zr[f];
    else { int i = (f - 64) >> 6, j = (f - 64) & 63; v = zr[i] * zr[j] * 0.125f; }
    feat[(size_t)t * FPOLY + f] = v;
}

__global__ __launch_bounds__(256) void phi2_bf16(
    const float* __restrict__ z, bf16* __restrict__ feat)
{
    const int f = blockIdx.x * 256 + threadIdx.x;
    const int t = blockIdx.y;
    if (f >= FPOLY) return;
    const float* zr = z + (size_t)t * 64;
    float v;
    if (f < 64) v = zr[f];
    else { int i = (f - 64) >> 6, j = (f - 64) & 63; v = zr[i] * zr[j] * 0.125f; }
    feat[(size_t)t * FPOLY + f] = (bf16)v;
}

__global__ void silu_kernel(const float* __restrict__ in, float* __restrict__ out, int n)
{
    int i = blockIdx.x * 256 + threadIdx.x;
    if (i < n) { float v = in[i]; out[i] = v / (1.f + expf(-v)); }
}

__global__ void dpred_kernel(const float* __restrict__ pred, const float* __restrict__ va,
                             const float* __restrict__ wvec, const float* __restrict__ wsum,
                             float* __restrict__ dpred)
{
    int i = blockIdx.x * 256 + threadIdx.x;
    if (i < NACT * Dc) {
        int t = i >> 10;
        dpred[i] = 2.f * wvec[t] / (wsum[0] + 1e-8f) * (pred[i] - va[i]);
    }
}

__global__ void dsilu_kernel(const float* __restrict__ dsu, const float* __restrict__ u,
                             float* __restrict__ du, int n)
{
    int i = blockIdx.x * 256 + threadIdx.x;
    if (i < n) {
        float uv = u[i];
        float sg = 1.f / (1.f + expf(-uv));
        du[i] = dsu[i] * sg * (1.f + uv * (1.f - sg));
    }
}

__global__ void dz_kernel(const float* __restrict__ dfeat, const float* __restrict__ za,
                          float* __restrict__ dz)
{
    const int t = blockIdx.x;
    const int k = threadIdx.x;
    const float* df = dfeat + (size_t)t * FPOLY;
    const float* z = za + (size_t)t * 64;
    float s1 = 0.f, s2 = 0.f;
    for (int j = 0; j < 64; ++j) {
        float zj = z[j];
        s1 += df[64 + k * 64 + j] * zj;
        s2 += df[64 + j * 64 + k] * zj;
    }
    dz[(size_t)t * 64 + k] = df[k] + 0.125f * (s1 + s2);
}

__global__ void add_diag_kernel(float* __restrict__ F)
{
    int i = threadIdx.x;
    F[i * 128 + i] += 3.4445f;
}

__global__ void zero_kernel(float* p, int n)
{
    int i = blockIdx.x * blockDim.x + threadIdx.x;
    if (i < n) p[i] = 0.f;
}

__global__ void dot_reduce(const float* __restrict__ a, const float* __restrict__ b,
                           int n, float* __restrict__ out)
{
    float s = 0.f;
    for (int i = blockIdx.x * blockDim.x + threadIdx.x; i < n; i += gridDim.x * blockDim.x)
        s += a[i] * b[i];
    __shared__ float red[256];
    const int t = threadIdx.x;
    red[t] = s; __syncthreads();
    for (int st = 128; st; st >>= 1) { if (t < st) red[t] += red[t + st]; __syncthreads(); }
    if (t == 0) atomicAdd(out, red[0]);
}

__global__ void scale_kernel(const float* __restrict__ src, float* __restrict__ dst,
                             int n, const float* __restrict__ ss)
{
    int i = blockIdx.x * 256 + threadIdx.x;
    if (i < n) dst[i] = src[i] / (sqrtf(ss[0]) + 1e-7f);
}

__global__ void sgate_kernel(const float* __restrict__ mg, float* __restrict__ out)
{
    out[0] = 1.f / (1.f + expf(-mg[0]));
}

// ff = silu-already ff1 * ff3, bf16 in-place into ff1; zero the K-pad cols
__global__ void mulpad_kernel(bf16* __restrict__ a, const bf16* __restrict__ b)
{
    int i = blockIdx.x * 256 + threadIdx.x;
    if (i >= NTOK * FFNHP) return;
    int k = i % FFNHP;
    if (k >= FFNH) { a[i] = (bf16)0.f; return; }
    a[i] = (bf16)((float)a[i] * (float)b[i]);
}

// ---------------------------------------------------------------- launch
extern "C" void kernel_launch(void* const* d_in, const int* in_sizes, int n_in,
                              void* d_out, int out_size, void* d_ws, size_t ws_size,
                              hipStream_t stream)
{
    const float* x     = (const float*)d_in[0];
    const float* n1w   = (const float*)d_in[1];
    const float* n2w   = (const float*)d_in[2];
    const float* qkvw  = (const float*)d_in[3];
    const float* qnw   = (const float*)d_in[4];
    const float* knw   = (const float*)d_in[5];
    const float* gw1   = (const float*)d_in[6];
    const float* gw2   = (const float*)d_in[7];
    const float* mwk   = (const float*)d_in[8];
    const float* mw1   = (const float*)d_in[9];
    const float* mw2   = (const float*)d_in[10];
    const float* mgate = (const float*)d_in[11];
    const float* wow   = (const float*)d_in[12];
    const float* fw1   = (const float*)d_in[13];
    const float* fw2   = (const float*)d_in[14];
    const float* fw3   = (const float*)d_in[15];
    float* outp = (float*)d_out;

    char* base = (char*)d_ws;
    size_t off = 0;
    auto takeB = [&](size_t bytes) { char* p = base + off; off += (bytes + 255) & ~(size_t)255; return p; };

    // slabs (liveness-overlaid)
    char* slabA  = takeB(22544384);  // featC (17.0MB) -> ff1b (22.5MB)
    char* slabBC = takeB(16777216);  // qnb+knb (8.39+8.39) -> x2 fp32 (16.78)
    char* slabD  = takeB(8388608);   // vb -> t1b/u (chunked)
    char* slabE  = takeB(22544384);  // qmem fp32 (16.78) -> ff3b (22.5)
    char* slabF  = takeB(8388608);   // qtb -> attnb
    char* slabG  = takeB(8388608);   // hb -> h2b
    bf16* featC = (bf16*)slabA;   bf16* ff1b = (bf16*)slabA;
    bf16* qnb = (bf16*)slabBC;    bf16* knb = (bf16*)(slabBC + 8388608);
    float* x2 = (float*)slabBC;
    bf16* vb = (bf16*)slabD;      bf16* t1b = (bf16*)slabD;
    float* qmem = (float*)slabE;  bf16* ff3b = (bf16*)slabE;
    bf16* qtb = (bf16*)slabF;     bf16* attnb = (bf16*)slabF;
    bf16* hb = (bf16*)slabG;      bf16* h2b = (bf16*)slabG;

    // bf16 weights (transposed to (N,K))
    bf16* qkvwT = (bf16*)takeB(6291456);    // (3072,1024)
    bf16* gw1T  = (bf16*)takeB(262144);     // (128 alloc / 64 real, 1024)
    bf16* wowT  = (bf16*)takeB(2097152);    // (1024,1024)
    bf16* mw1T  = (bf16*)takeB(17039360);   // (2048,4160)
    bf16* mw2T  = (bf16*)takeB(4194304);    // (1024,2048)
    bf16* fw1T  = (bf16*)takeB(5767168);    // (2816 alloc / 2730 real, 1024)
    bf16* fw3T  = (bf16*)takeB(5767168);
    bf16* fw2T  = (bf16*)takeB(5636096);    // (1024, 2752 zero-padded)

    // fp32 misc
    float* zf    = (float*)takeB(1048576);
    float* gg1   = (float*)takeB(1048576);
    float* gamma = (float*)takeB(16384);
    float* wvec  = (float*)takeB(512);
    float* scal  = (float*)takeB(256);      // [0]=wsum [1]=ns-norm^2 [2]=sigmoid(gate)
    float* xa    = (float*)takeB(524288);
    float* va    = (float*)takeB(524288);
    float* za    = (float*)takeB(32768);
    float* featA = (float*)takeB(2129920);
    float* ua    = (float*)takeB(1048576);
    float* sua   = (float*)takeB(1048576);
    float* preda = (float*)takeB(524288);
    float* dpreda= (float*)takeB(524288);
    float* dsua  = (float*)takeB(1048576);
    float* dua   = (float*)takeB(1048576);
    float* dfeata= (float*)takeB(2129920);
    float* dza   = (float*)takeB(32768);
    float* Sb    = (float*)takeB(65536);
    float* Gb    = (float*)takeB(65536);
    float* Mb    = (float*)takeB(65536);
    float* Fb    = (float*)takeB(65536);
    float* Tb    = (float*)takeB(1048576);
    float* PTa   = (float*)takeB(1048576);
    float* PT1   = (float*)takeB(1048576);
    float* PT2   = (float*)takeB(524288);
    float* PT3   = (float*)takeB(32768);
    float* wku   = (float*)takeB(262144);
    // bf16 misc
    bf16* featAb = (bf16*)takeB(1064960);
    bf16* suab   = (bf16*)takeB(524288);
    bf16* PT1Tb  = (bf16*)takeB(524288);    // (2048,128)
    bf16* PT2Tb  = (bf16*)takeB(262144);    // (1024,128)
    bf16* tBb    = (bf16*)takeB(524288);    // (2048,128) per chunk

    auto gemmF = [&](int TA, int TB, const float* A, const float* B, const float* Cin, float* C,
                     int M, int N, int K, int lda, int ldb, int ldc,
                     float alpha, float beta, int act) {
        dim3 grid((N + 63) / 64, (M + 63) / 64);
        if (!TA && !TB)      gemm_f32<0, 0><<<grid, 256, 0, stream>>>(A, B, Cin, C, M, N, K, lda, ldb, ldc, alpha, beta, act);
        else if (!TA && TB)  gemm_f32<0, 1><<<grid, 256, 0, stream>>>(A, B, Cin, C, M, N, K, lda, ldb, ldc, alpha, beta, act);
        else if (TA && !TB)  gemm_f32<1, 0><<<grid, 256, 0, stream>>>(A, B, Cin, C, M, N, K, lda, ldb, ldc, alpha, beta, act);
        else                 gemm_f32<1, 1><<<grid, 256, 0, stream>>>(A, B, Cin, C, M, N, K, lda, ldb, ldc, alpha, beta, act);
    };
    auto gemmB = [&](int outbf, int cinbf, const bf16* A, const bf16* Bt,
                     const void* Cin, void* C, int M, int N, int K, int ldc,
                     float alpha, float beta, int act, const float* sptr) {
        dim3 grid((N + 127) / 128, M / 128);
        if (outbf && cinbf) gemm_bt<1, 1><<<grid, 256, 0, stream>>>(A, Bt, Cin, C, M, N, K, ldc, alpha, beta, act, sptr);
        else if (outbf)     gemm_bt<1, 0><<<grid, 256, 0, stream>>>(A, Bt, Cin, C, M, N, K, ldc, alpha, beta, act, sptr);
        else                gemm_bt<0, 0><<<grid, 256, 0, stream>>>(A, Bt, Cin, C, M, N, K, ldc, alpha, beta, act, sptr);
    };
    auto tconv = [&](const float* W, bf16* Wt, int K, int N, int Kpad) {
        tconv_kernel<<<dim3((Kpad + 31) / 32, (N + 31) / 32), 256, 0, stream>>>(W, Wt, K, N, Kpad);
    };

    // 0. weight transpose-converts
    tconv(qkvw, qkvwT, Dc, 3 * Dc, Dc);
    tconv(gw1, gw1T, Dc, GGH, Dc);
    tconv(wow, wowT, Dc, Dc, Dc);
    tconv(mw1, mw1T, FPOLY, MHID, FPOLY);
    tconv(mw2, mw2T, MHID, Dc, MHID);
    tconv(fw1, fw1T, Dc, FFNH, Dc);
    tconv(fw3, fw3T, Dc, FFNH, Dc);
    tconv(fw2, fw2T, FFNH, Dc, FFNHP);
    sgate_kernel<<<1, 1, 0, stream>>>(mgate, scal + 2);

    // 1. h = rmsnorm(x) -> bf16
    rms_rows<<<NTOK, 256, 0, stream>>>(x, n1w, hb, Dc);
    // 2. q/k/v + gamma
    gemmB(1, 0, hb, qkvwT,          nullptr, qtb, NTOK, Dc, Dc, Dc, 1.f, 0.f, 0, nullptr);
    snr_one<<<dim3(Sc / 4, Hc, Bc), 256, 0, stream>>>(qtb, qnw, qnb);
    gemmB(1, 0, hb, qkvwT + (size_t)1024 * Dc, nullptr, qtb, NTOK, Dc, Dc, Dc, 1.f, 0.f, 0, nullptr);
    snr_one<<<dim3(Sc / 4, Hc, Bc), 256, 0, stream>>>(qtb, knw, knb);
    gemmB(1, 0, hb, qkvwT + (size_t)2048 * Dc, nullptr, vb, NTOK, Dc, Dc, Dc, 1.f, 0.f, 0, nullptr);
    gemmB(0, 0, hb, gw1T, nullptr, gg1, NTOK, GGH, Dc, GGH, 1.f, 0.f, 0, nullptr);
    gamma_kernel<<<NTOK / 4, 256, 0, stream>>>(gg1, gw2, gamma);
    // 3. q_mem + attention
    qmem_kernel<<<dim3(Bc * Hc, 16), 64, 0, stream>>>(qnb, knb, gamma, qmem);
    attn_kernel<<<dim3(Sc / 64, Hc, Bc), 256, 0, stream>>>(qnb, knb, vb, attnb);
    // 4. gather actives (qnb/knb dead after this point -> x2 overlay legal)
    gather_active<<<NACT, 256, 0, stream>>>(qmem, vb, xa, va);
    wvec_kernel<<<1, 128, 0, stream>>>(gamma, wvec, scal);
    // 5. gradient chain on 128 active tokens
    gemmF(0, 0, xa, mwk, nullptr, za, NACT, HDc, Dc, Dc, HDc, HDc, 1.f, 0.f, 0);
    phi2_f32<<<dim3((FPOLY + 255) / 256, NACT), 256, 0, stream>>>(za, featA);
    cvt_kernel<<<520, 256, 0, stream>>>(featA, featAb, NACT * FPOLY);
    gemmB(0, 0, featAb, mw1T, nullptr, ua, NACT, MHID, FPOLY, MHID, 1.f, 0.f, 0, nullptr);
    silu_kernel<<<(NACT * MHID + 255) / 256, 256, 0, stream>>>(ua, sua, NACT * MHID);
    cvt_kernel<<<256, 256, 0, stream>>>(sua, suab, NACT * MHID);
    gemmB(0, 0, suab, mw2T, nullptr, preda, NACT, Dc, MHID, Dc, 1.f, 0.f, 0, nullptr);
    dpred_kernel<<<(NACT * Dc + 255) / 256, 256, 0, stream>>>(preda, va, wvec, scal, dpreda);
    gemmF(0, 1, dpreda, mw2, nullptr, dsua, NACT, MHID, Dc, Dc, Dc, MHID, 1.f, 0.f, 0);
    dsilu_kernel<<<(NACT * MHID + 255) / 256, 256, 0, stream>>>(dsua, ua, dua, NACT * MHID);
    gemmF(0, 1, dua, mw1, nullptr, dfeata, NACT, FPOLY, MHID, MHID, MHID, FPOLY, 1.f, 0.f, 0);
    dz_kernel<<<NACT, 64, 0, stream>>>(dfeata, za, dza);

    // 6. low-rank Newton-Schulz (fp32): PT' = F^T PT, F = aI+bM+cM^2, M=(QQ^T)(P^T P)
    auto ns_lowrank = [&](const float* Q, int nq, const float* PTraw, int np, float* outb) {
        gemmF(0, 1, Q, Q, nullptr, Sb, 128, 128, nq, nq, nq, 128, 1.f, 0.f, 0);
        gemmF(0, 0, Sb, PTraw, nullptr, Tb, 128, np, 128, 128, np, np, 1.f, 0.f, 0);
        zero_kernel<<<1, 64, 0, stream>>>(scal + 1, 1);
        dot_reduce<<<64, 256, 0, stream>>>(Tb, PTraw, 128 * np, scal + 1);
        scale_kernel<<<(128 * np + 255) / 256, 256, 0, stream>>>(PTraw, PTa, 128 * np, scal + 1);
        float* cur = PTa; float* alt = outb;
        for (int it = 0; it < 5; ++it) {
            gemmF(0, 1, cur, cur, nullptr, Gb, 128, 128, np, np, np, 128, 1.f, 0.f, 0);
            gemmF(0, 0, Sb, Gb, nullptr, Mb, 128, 128, 128, 128, 128, 128, 1.f, 0.f, 0);
            gemmF(0, 0, Mb, Mb, Mb, Fb, 128, 128, 128, 128, 128, 128, 2.0315f, -4.775f, 0);
            add_diag_kernel<<<1, 128, 0, stream>>>(Fb);
            gemmF(1, 0, Fb, cur, nullptr, alt, 128, np, 128, 128, np, np, 1.f, 0.f, 0);
            float* t = cur; cur = alt; alt = t;
        }
    };
    ns_lowrank(featA, FPOLY, dua, MHID, PT1);
    ns_lowrank(sua, MHID, dpreda, Dc, PT2);
    ns_lowrank(xa, Dc, dza, HDc, PT3);
    tconv(PT1, PT1Tb, 128, MHID, 128);
    tconv(PT2, PT2Tb, 128, Dc, 128);
    gemmF(1, 0, xa, PT3, mwk, wku, Dc, HDc, 128, Dc, HDc, HDc, -0.01f, 0.999f, 0);

    // 7. zf = qmem @ wku  (fp32, N=64); then qmem dead
    gemmF(0, 0, qmem, wku, nullptr, zf, NTOK, HDc, Dc, Dc, HDc, HDc, 1.f, 0.f, 0);
    // 8. x2 = x + attn@wo   (x2 overlays qnb/knb -- both dead)
    gemmB(0, 0, attnb, wowT, x, x2, NTOK, Dc, Dc, Dc, 1.f, 1.f, 0, nullptr);
    // 9. memory forward (low-rank updated weights), 2 chunks of 2048 tokens
    for (int c = 0; c < NTOK / MCH; ++c) {
        const int R = c * MCH;
        phi2_bf16<<<dim3((FPOLY + 255) / 256, MCH), 256, 0, stream>>>(zf + (size_t)R * HDc, featC);
        // u = 0.999*feat@mw1 - 0.01*(feat@featA^T)@PT1 ; t1 = silu(u)
        gemmB(1, 0, featC, mw1T, nullptr, t1b, MCH, MHID, FPOLY, MHID, 0.999f, 0.f, 0, nullptr);
        gemmB(1, 0, featC, featAb, nullptr, tBb, MCH, NACT, FPOLY, NACT, 1.f, 0.f, 0, nullptr);
        gemmB(1, 1, tBb, PT1Tb, t1b, t1b, MCH, MHID, NACT, MHID, -0.01f, 1.f, 1, nullptr);
        // x2 += sg * (0.999*t1@mw2 - 0.01*(t1@sua^T)@PT2)
        gemmB(0, 0, t1b, mw2T, x2 + (size_t)R * Dc, x2 + (size_t)R * Dc,
              MCH, Dc, MHID, Dc, 0.999f, 1.f, 0, scal + 2);
        gemmB(1, 0, t1b, suab, nullptr, tBb, MCH, NACT, MHID, NACT, 1.f, 0.f, 0, nullptr);
        gemmB(0, 0, tBb, PT2Tb, x2 + (size_t)R * Dc, x2 + (size_t)R * Dc,
              MCH, Dc, NACT, Dc, -0.01f, 1.f, 0, scal + 2);
    }
    // 10. FFN (swiglu)
    rms_rows<<<NTOK, 256, 0, stream>>>(x2, n2w, h2b, Dc);
    gemmB(1, 0, h2b, fw1T, nullptr, ff1b, NTOK, FFNH, Dc, FFNHP, 1.f, 0.f, 1, nullptr);
    gemmB(1, 0, h2b, fw3T, nullptr, ff3b, NTOK, FFNH, Dc, FFNHP, 1.f, 0.f, 0, nullptr);
    mulpad_kernel<<<(NTOK * FFNHP + 255) / 256, 256, 0, stream>>>(ff1b, ff3b);
    gemmB(0, 0, ff1b, fw2T, x2, outp, NTOK, Dc, FFNHP, Dc, 1.f, 1.f, 0, nullptr);
}

// Round 4
// 2473.950 us; speedup vs baseline: 11.5671x; 3.0666x over previous
//
#include <hip/hip_runtime.h>
#include <math.h>

#define Bc 2
#define Sc 2048
#define Dc 1024
#define Hc 16
#define HDc 64
#define FPOLY 4160
#define MHID 2048
#define FFNH 2730
#define FFNHP 2752   // FFNH padded to mult of 32 (K pad, zero-filled)
#define GGH 64
#define NTOK 4096
#define NACT 128
#define MCH 2048     // memory-forward M chunk

typedef __bf16 bf16;
typedef __attribute__((ext_vector_type(8))) __bf16 bf16x8;
typedef __attribute__((ext_vector_type(4))) float f32x4;

#define AS1 __attribute__((address_space(1)))
#define AS3 __attribute__((address_space(3)))

__device__ __forceinline__ void gload16(const void* g, void* l) {
    __builtin_amdgcn_global_load_lds((AS1 const void*)g, (AS3 void*)l, 16, 0, 0);
}

// ---------------------------------------------------------------- bf16 MFMA GEMM
// C = act(alpha*[sptr]*A@Bt^T + beta*Cin).  A:(M,K) bf16 row-major, Bt:(N,K) bf16
// row-major. K%32==0, M%128==0. N arbitrary (col-masked stores); Bt rows allocated
// to ceil(N/128)*128.
template<int OUTBF, int CINBF>
__global__ __launch_bounds__(256) void gemm_bt(
    const bf16* __restrict__ A, const bf16* __restrict__ Bt,
    const void* __restrict__ Cin, void* __restrict__ Cout,
    int M, int N, int K, int ldc,
    float alpha, float beta, int act, const float* __restrict__ sptr)
{
    __shared__ bf16 As[128 * 32];
    __shared__ bf16 Bs[128 * 32];
    const int tid = threadIdx.x;
    const int w = tid >> 6, lane = tid & 63;
    const int bm = blockIdx.y * 128, bn = blockIdx.x * 128;
    const int wm = (w >> 1) * 64, wn = (w & 1) * 64;
    f32x4 acc[4][4];
#pragma unroll
    for (int i = 0; i < 4; ++i)
#pragma unroll
        for (int j = 0; j < 4; ++j) { acc[i][j][0] = 0.f; acc[i][j][1] = 0.f; acc[i][j][2] = 0.f; acc[i][j][3] = 0.f; }
    const int idx0 = tid, idx1 = tid + 256;
    const int r0 = idx0 >> 2, r1 = idx1 >> 2;
    const int g0 = ((idx0 & 3) ^ ((r0 >> 1) & 3)) * 8;
    const int g1 = ((idx1 & 3) ^ ((r1 >> 1) & 3)) * 8;
    char* ldsA0 = (char*)As + w * 1024;
    char* ldsB0 = (char*)Bs + w * 1024;
    const int lrow = lane & 15;
    const int q = lane >> 4;
    int aoff[4], boff[4];
#pragma unroll
    for (int t = 0; t < 4; ++t) {
        int ar = wm + t * 16 + lrow;
        aoff[t] = ar * 32 + ((q ^ ((ar >> 1) & 3)) * 8);
        int br = wn + t * 16 + lrow;
        boff[t] = br * 32 + ((q ^ ((br >> 1) & 3)) * 8);
    }
    const bf16* Arow0 = A + (size_t)(bm + r0) * K + g0;
    const bf16* Arow1 = A + (size_t)(bm + r1) * K + g1;
    const bf16* Brow0 = Bt + (size_t)(bn + r0) * K + g0;
    const bf16* Brow1 = Bt + (size_t)(bn + r1) * K + g1;
    for (int k0 = 0; k0 < K; k0 += 32) {
        gload16(Arow0 + k0, ldsA0);
        gload16(Arow1 + k0, ldsA0 + 4096);
        gload16(Brow0 + k0, ldsB0);
        gload16(Brow1 + k0, ldsB0 + 4096);
        __syncthreads();
        bf16x8 af[4], bfr[4];
#pragma unroll
        for (int t = 0; t < 4; ++t) af[t] = *(const bf16x8*)&As[aoff[t]];
#pragma unroll
        for (int t = 0; t < 4; ++t) bfr[t] = *(const bf16x8*)&Bs[boff[t]];
#pragma unroll
        for (int mt = 0; mt < 4; ++mt)
#pragma unroll
            for (int nt = 0; nt < 4; ++nt)
                acc[mt][nt] = __builtin_amdgcn_mfma_f32_16x16x32_bf16(af[mt], bfr[nt], acc[mt][nt], 0, 0, 0);
        __syncthreads();
    }
    const float amul = alpha * (sptr ? *sptr : 1.f);
#pragma unroll
    for (int nt = 0; nt < 4; ++nt) {
        const int col = bn + wn + nt * 16 + lrow;
        if (col >= N) continue;
#pragma unroll
        for (int mt = 0; mt < 4; ++mt) {
            const int rbase = bm + wm + mt * 16 + q * 4;
#pragma unroll
            for (int r = 0; r < 4; ++r) {
                const size_t o = (size_t)(rbase + r) * ldc + col;
                float v = amul * acc[mt][nt][r];
                if (beta != 0.f)
                    v += beta * (CINBF ? (float)((const bf16*)Cin)[o] : ((const float*)Cin)[o]);
                if (act == 1) v = v / (1.f + __expf(-v));
                if (OUTBF) ((bf16*)Cout)[o] = (bf16)v;
                else       ((float*)Cout)[o] = v;
            }
        }
    }
}

// ---------------------------------------------------------------- fp32 GEMM (small/precision paths)
template<int TA, int TB>
__global__ __launch_bounds__(256) void gemm_f32(
    const float* __restrict__ A, const float* __restrict__ B,
    const float* __restrict__ Cin, float* __restrict__ C,
    int M, int N, int K, int lda, int ldb, int ldc,
    float alpha, float beta, int act, const float* __restrict__ sA)
{
    __shared__ float As[16][68];
    __shared__ float Bs[16][68];
    const int bm = blockIdx.y * 64;
    const int bn = blockIdx.x * 64;
    const int tid = threadIdx.x;
    const int tx = tid & 15;
    const int ty = tid >> 4;
    float acc[4][4];
#pragma unroll
    for (int i = 0; i < 4; ++i)
#pragma unroll
        for (int j = 0; j < 4; ++j) acc[i][j] = 0.f;
    for (int k0 = 0; k0 < K; k0 += 16) {
#pragma unroll
        for (int l = 0; l < 4; ++l) {
            int i = tid + l * 256;
            int m, kk;
            if (TA) { m = i & 63; kk = i >> 6; } else { kk = i & 15; m = i >> 4; }
            int gm = bm + m, gk = k0 + kk;
            float v = 0.f;
            if (gm < M && gk < K)
                v = TA ? A[(size_t)gk * lda + gm] : A[(size_t)gm * lda + gk];
            As[kk][m] = v;
        }
#pragma unroll
        for (int l = 0; l < 4; ++l) {
            int i = tid + l * 256;
            int n, kk;
            if (TB) { kk = i & 15; n = i >> 4; } else { n = i & 63; kk = i >> 6; }
            int gn = bn + n, gk = k0 + kk;
            float v = 0.f;
            if (gn < N && gk < K)
                v = TB ? B[(size_t)gn * ldb + gk] : B[(size_t)gk * ldb + gn];
            Bs[kk][n] = v;
        }
        __syncthreads();
#pragma unroll
        for (int kk = 0; kk < 16; ++kk) {
            float4 a4 = *(const float4*)&As[kk][ty * 4];
            float4 b4 = *(const float4*)&Bs[kk][tx * 4];
            float av[4] = {a4.x, a4.y, a4.z, a4.w};
            float bv[4] = {b4.x, b4.y, b4.z, b4.w};
#pragma unroll
            for (int i2 = 0; i2 < 4; ++i2)
#pragma unroll
                for (int j2 = 0; j2 < 4; ++j2) acc[i2][j2] += av[i2] * bv[j2];
        }
        __syncthreads();
    }
    const float amul = alpha * (sA ? sA[0] : 1.f);
#pragma unroll
    for (int i2 = 0; i2 < 4; ++i2) {
        int gm = bm + ty * 4 + i2;
        if (gm >= M) continue;
#pragma unroll
        for (int j2 = 0; j2 < 4; ++j2) {
            int gn = bn + tx * 4 + j2;
            if (gn >= N) continue;
            float v = amul * acc[i2][j2];
            if (beta != 0.f) v += beta * Cin[(size_t)gm * ldc + gn];
            if (act == 1) v = v / (1.f + __expf(-v));
            C[(size_t)gm * ldc + gn] = v;
        }
    }
}

// ---------------------------------------------------------------- batched 128x128x128 fp32
// C[z] = alpha*op(A)[z]@B[z] + beta*Min[z] + dg*I
template<int TRA>
__global__ __launch_bounds__(256) void b128mm(
    const float* __restrict__ Ab, const float* __restrict__ Bb,
    const float* __restrict__ Min, float* __restrict__ Cb,
    float alpha, float beta, float dg)
{
    const int z = blockIdx.z;
    const float* A = Ab + (size_t)z * 16384;
    const float* B = Bb + (size_t)z * 16384;
    float* C = Cb + (size_t)z * 16384;
    __shared__ float As[16][68];
    __shared__ float Bs[16][68];
    const int bm = blockIdx.y * 64, bn = blockIdx.x * 64;
    const int tid = threadIdx.x, tx = tid & 15, ty = tid >> 4;
    float acc[4][4];
#pragma unroll
    for (int i = 0; i < 4; ++i)
#pragma unroll
        for (int j = 0; j < 4; ++j) acc[i][j] = 0.f;
    for (int k0 = 0; k0 < 128; k0 += 16) {
#pragma unroll
        for (int l = 0; l < 4; ++l) {
            int i = tid + l * 256;
            int m, kk;
            if (TRA) { m = i & 63; kk = i >> 6; } else { kk = i & 15; m = i >> 4; }
            As[kk][m] = TRA ? A[(k0 + kk) * 128 + bm + m] : A[(bm + m) * 128 + k0 + kk];
        }
#pragma unroll
        for (int l = 0; l < 4; ++l) {
            int i = tid + l * 256;
            int n = i & 63, kk = i >> 6;
            Bs[kk][n] = B[(k0 + kk) * 128 + bn + n];
        }
        __syncthreads();
#pragma unroll
        for (int kk = 0; kk < 16; ++kk) {
            float4 a4 = *(const float4*)&As[kk][ty * 4];
            float4 b4 = *(const float4*)&Bs[kk][tx * 4];
            float av[4] = {a4.x, a4.y, a4.z, a4.w};
            float bv[4] = {b4.x, b4.y, b4.z, b4.w};
#pragma unroll
            for (int i2 = 0; i2 < 4; ++i2)
#pragma unroll
                for (int j2 = 0; j2 < 4; ++j2) acc[i2][j2] += av[i2] * bv[j2];
        }
        __syncthreads();
    }
#pragma unroll
    for (int i2 = 0; i2 < 4; ++i2) {
        int gm = bm + ty * 4 + i2;
#pragma unroll
        for (int j2 = 0; j2 < 4; ++j2) {
            int gn = bn + tx * 4 + j2;
            float v = alpha * acc[i2][j2];
            if (beta != 0.f) v += beta * Min[(size_t)z * 16384 + gm * 128 + gn];
            if (dg != 0.f && gm == gn) v += dg;
            C[gm * 128 + gn] = v;
        }
    }
}

// per-batch: n2 = <S[z],C[z]>; C[z] *= inv^2; invn[z] = 1/(sqrt(n2)+1e-7)
__global__ __launch_bounds__(256) void ns_norm_kernel(
    const float* __restrict__ S, float* __restrict__ C, float* __restrict__ invn)
{
    const int z = blockIdx.x;
    const float* s = S + (size_t)z * 16384;
    float* c = C + (size_t)z * 16384;
    float acc = 0.f;
    for (int i = threadIdx.x; i < 16384; i += 256) acc += s[i] * c[i];
    __shared__ float red[256];
    red[threadIdx.x] = acc; __syncthreads();
    for (int st = 128; st; st >>= 1) {
        if (threadIdx.x < st) red[threadIdx.x] += red[threadIdx.x + st];
        __syncthreads();
    }
    float inv = 1.f / (sqrtf(red[0]) + 1e-7f);
    float inv2 = inv * inv;
    for (int i = threadIdx.x; i < 16384; i += 256) c[i] *= inv2;
    if (threadIdx.x == 0) invn[z] = inv;
}

// ---------------------------------------------------------------- converts
__global__ __launch_bounds__(256) void tconv_kernel(
    const float* __restrict__ W, bf16* __restrict__ Wt, int K, int N, int Kpad)
{
    __shared__ float t[32][33];
    const int k0 = blockIdx.x * 32, n0 = blockIdx.y * 32;
    const int tx = threadIdx.x & 31, ty = threadIdx.x >> 5;
#pragma unroll
    for (int r = 0; r < 4; ++r) {
        int gk = k0 + ty + r * 8, gn = n0 + tx;
        t[ty + r * 8][tx] = (gk < K && gn < N) ? W[(size_t)gk * N + gn] : 0.f;
    }
    __syncthreads();
#pragma unroll
    for (int r = 0; r < 4; ++r) {
        int gn = n0 + ty + r * 8, gk = k0 + tx;
        if (gn < N && gk < Kpad) Wt[(size_t)gn * Kpad + gk] = (bf16)t[tx][ty + r * 8];
    }
}

__global__ void cvt_kernel(const float* __restrict__ in, bf16* __restrict__ out, int n)
{
    for (int i = blockIdx.x * 256 + threadIdx.x; i < n; i += gridDim.x * 256)
        out[i] = (bf16)in[i];
}

// vb (b,s,h,d) -> vt (b,h,d,s)
__global__ __launch_bounds__(256) void vtrans_kernel(
    const bf16* __restrict__ vb, bf16* __restrict__ vt)
{
    __shared__ bf16 t[32][33];
    const int s0 = blockIdx.x * 32, d0 = blockIdx.y * 32, bh = blockIdx.z;
    const int b = bh >> 4, h = bh & 15;
    const int tx = threadIdx.x & 31, ty = threadIdx.x >> 5;
#pragma unroll
    for (int r = 0; r < 4; ++r) {
        int s = s0 + ty + r * 8;
        t[ty + r * 8][tx] = vb[((size_t)b * Sc + s) * Dc + h * 64 + d0 + tx];
    }
    __syncthreads();
#pragma unroll
    for (int r = 0; r < 4; ++r) {
        int d = d0 + ty + r * 8;
        vt[((size_t)bh * 64 + d) * Sc + s0 + tx] = t[tx][ty + r * 8];
    }
}

// ---------------------------------------------------------------- small kernels
__global__ __launch_bounds__(256) void rms_rows(
    const float* __restrict__ in, const float* __restrict__ w,
    bf16* __restrict__ out, int D)
{
    const int row = blockIdx.x;
    const float* r = in + (size_t)row * D;
    bf16* o = out + (size_t)row * D;
    float s = 0.f;
    for (int i = threadIdx.x; i < D; i += 256) { float v = r[i]; s += v * v; }
    __shared__ float red[256];
    red[threadIdx.x] = s;
    __syncthreads();
    for (int st = 128; st; st >>= 1) {
        if (threadIdx.x < st) red[threadIdx.x] += red[threadIdx.x + st];
        __syncthreads();
    }
    float rs = rsqrtf(red[0] / (float)D + 1e-6f);
    for (int i = threadIdx.x; i < D; i += 256) o[i] = (bf16)(r[i] * rs * w[i]);
}

__global__ __launch_bounds__(256) void gamma_kernel(
    const float* __restrict__ gg1, const float* __restrict__ w2,
    float* __restrict__ gamma)
{
    const int tid = threadIdx.x, w = tid >> 6, lane = tid & 63;
    const int t = blockIdx.x * 4 + w;
    float v = gg1[(size_t)t * GGH + lane];
    v = v / (1.f + expf(-v));
    v *= w2[lane];
#pragma unroll
    for (int off = 32; off; off >>= 1) v += __shfl_xor(v, off);
    if (lane == 0) gamma[t] = 1.f / (1.f + expf(-v));
}

__global__ __launch_bounds__(256) void snr_one(
    const bf16* __restrict__ src, const float* __restrict__ w,
    bf16* __restrict__ dst)
{
    const int tid = threadIdx.x, wv = tid >> 6, lane = tid & 63;
    const int s = blockIdx.x * 4 + wv;
    const int h = blockIdx.y, b = blockIdx.z;
    const size_t row = ((size_t)b * Sc + s) * Dc + h * 64;
    float v = (float)src[row + lane];
    float ss = v * v;
#pragma unroll
    for (int off = 32; off; off >>= 1) ss += __shfl_xor(ss, off);
    v = v * rsqrtf(ss / 64.f + 1e-6f) * w[lane];
    const int j = lane & 31;
    float inv = powf(10000.f, -(float)j / 32.f);
    float ang = (float)s * inv;
    float sn = sinf(ang), cs = cosf(ang);
    float p = __shfl_xor(v, 32);
    float o;
    if (lane < 32) o = v * cs - p * sn;
    else           o = p * sn + v * cs;
    const size_t od = (((size_t)b * Hc + h) * Sc + s) * 64 + lane;
    dst[od] = (bf16)o;
}

// phase 1: psum[bh][c][d] = sum over the c-th 128-block of kn
__global__ void kpsum_kernel(const bf16* __restrict__ kn, float* __restrict__ psum)
{
    const int bh = blockIdx.x, c = blockIdx.y, d = threadIdx.x;
    const size_t base = (size_t)bh * Sc * 64 + (size_t)c * 128 * 64 + d;
    float s = 0.f;
    for (int i = 0; i < 128; ++i) s += (float)kn[base + (size_t)i * 64];
    psum[((size_t)bh * 16 + c) * 64 + d] = s;
}

// phase 2: cumulative-mean mix using psum prefix
__global__ void qmem2_kernel(
    const bf16* __restrict__ qn, const bf16* __restrict__ kn,
    const float* __restrict__ gamma, const float* __restrict__ psum,
    float* __restrict__ qmem)
{
    const int bh = blockIdx.x, c = blockIdx.y;
    const int b = bh >> 4, hh = bh & 15;
    const int d = threadIdx.x;
    const size_t base = (size_t)bh * Sc * 64;
    float run = 0.f;
    for (int cc = 0; cc < c; ++cc) run += psum[((size_t)bh * 16 + cc) * 64 + d];
    for (int s = c * 128; s < c * 128 + 128; ++s) {
        run += (float)kn[base + (size_t)s * 64 + d];
        float cm = run / (float)(s + 1);
        float g = gamma[b * Sc + s];
        float qv = (float)qn[base + (size_t)s * 64 + d];
        qmem[((size_t)(b * Sc + s)) * Dc + hh * 64 + d] = g * qv + (1.f - g) * cm;
    }
}

// ---------------------------------------------------------------- MFMA flash attention
// qn,kn: (bh, s, 64) bf16.  vt: (bh, 64, s) bf16.  out: (b, s, h*64+d) bf16.
// block = 128 q-rows, 4 waves x 32 rows. No barriers (P staging is per-wave).
__global__ __launch_bounds__(256) void attn_mfma(
    const bf16* __restrict__ qn, const bf16* __restrict__ kn,
    const bf16* __restrict__ vt, bf16* __restrict__ outp)
{
    const int qt = blockIdx.x;
    const int h = blockIdx.y, b = blockIdx.z;
    const int bh = b * Hc + h;
    const int tid = threadIdx.x, w = tid >> 6, lane = tid & 63;
    const int lrow = lane & 15, quad = lane >> 4;
    const int qb = qt * 128;
    const int wq = w * 32;
    __shared__ bf16 Ps[4][32][136];
    // Q fragments (A-layout): 2 mtiles x 2 ksteps
    bf16x8 qf[2][2];
    const bf16* qbase = qn + ((size_t)bh * Sc + qb + wq) * 64;
#pragma unroll
    for (int mt = 0; mt < 2; ++mt)
#pragma unroll
        for (int ks = 0; ks < 2; ++ks)
            qf[mt][ks] = *(const bf16x8*)(qbase + (size_t)(mt * 16 + lrow) * 64 + ks * 32 + quad * 8);
    f32x4 oacc[2][4];
#pragma unroll
    for (int mt = 0; mt < 2; ++mt)
#pragma unroll
        for (int nt = 0; nt < 4; ++nt) { oacc[mt][nt][0] = 0.f; oacc[mt][nt][1] = 0.f; oacc[mt][nt][2] = 0.f; oacc[mt][nt][3] = 0.f; }
    float m_i[2][4], l_i[2][4];
#pragma unroll
    for (int mt = 0; mt < 2; ++mt)
#pragma unroll
        for (int r = 0; r < 4; ++r) { m_i[mt][r] = -1e30f; l_i[mt][r] = 0.f; }
    const bf16* kbase = kn + (size_t)bh * Sc * 64;
    const bf16* vtb = vt + (size_t)bh * 64 * Sc;
    for (int k0 = 0; k0 <= qb; k0 += 128) {
        f32x4 sacc[2][8];
#pragma unroll
        for (int mt = 0; mt < 2; ++mt)
#pragma unroll
            for (int nt = 0; nt < 8; ++nt) { sacc[mt][nt][0] = 0.f; sacc[mt][nt][1] = 0.f; sacc[mt][nt][2] = 0.f; sacc[mt][nt][3] = 0.f; }
#pragma unroll
        for (int ks = 0; ks < 2; ++ks) {
            bf16x8 kf[8];
#pragma unroll
            for (int nt = 0; nt < 8; ++nt)
                kf[nt] = *(const bf16x8*)(kbase + (size_t)(k0 + nt * 16 + lrow) * 64 + ks * 32 + quad * 8);
#pragma unroll
            for (int mt = 0; mt < 2; ++mt)
#pragma unroll
                for (int nt = 0; nt < 8; ++nt)
                    sacc[mt][nt] = __builtin_amdgcn_mfma_f32_16x16x32_bf16(qf[mt][ks], kf[nt], sacc[mt][nt], 0, 0, 0);
        }
        const bool diag = (k0 == qb);
#pragma unroll
        for (int mt = 0; mt < 2; ++mt) {
            float mx[4] = {-1e30f, -1e30f, -1e30f, -1e30f};
#pragma unroll
            for (int nt = 0; nt < 8; ++nt) {
                int kc = k0 + nt * 16 + lrow;
#pragma unroll
                for (int r = 0; r < 4; ++r) {
                    float v = sacc[mt][nt][r] * 0.125f;
                    if (diag && kc > qb + wq + mt * 16 + quad * 4 + r) v = -1e30f;
                    sacc[mt][nt][r] = v;
                    mx[r] = fmaxf(mx[r], v);
                }
            }
#pragma unroll
            for (int r = 0; r < 4; ++r) {
#pragma unroll
                for (int off = 1; off < 16; off <<= 1) mx[r] = fmaxf(mx[r], __shfl_xor(mx[r], off));
                float mnew = fmaxf(m_i[mt][r], mx[r]);
                float corr = __expf(m_i[mt][r] - mnew);
                m_i[mt][r] = mnew;
                l_i[mt][r] *= corr;
#pragma unroll
                for (int nt2 = 0; nt2 < 4; ++nt2) oacc[mt][nt2][r] *= corr;
            }
            float sum[4] = {0.f, 0.f, 0.f, 0.f};
#pragma unroll
            for (int nt = 0; nt < 8; ++nt)
#pragma unroll
                for (int r = 0; r < 4; ++r) {
                    float p = __expf(sacc[mt][nt][r] - m_i[mt][r]);
                    sacc[mt][nt][r] = p;
                    sum[r] += p;
                }
#pragma unroll
            for (int r = 0; r < 4; ++r) {
#pragma unroll
                for (int off = 1; off < 16; off <<= 1) sum[r] += __shfl_xor(sum[r], off);
                l_i[mt][r] += sum[r];
            }
#pragma unroll
            for (int nt = 0; nt < 8; ++nt)
#pragma unroll
                for (int r = 0; r < 4; ++r)
                    Ps[w][mt * 16 + quad * 4 + r][nt * 16 + lrow] = (bf16)sacc[mt][nt][r];
        }
        // PV: A from Ps (own wave region -- wave-internal ordering only), B from vt
#pragma unroll
        for (int ks = 0; ks < 4; ++ks) {
            bf16x8 pf[2];
#pragma unroll
            for (int mt = 0; mt < 2; ++mt)
                pf[mt] = *(const bf16x8*)&Ps[w][mt * 16 + lrow][ks * 32 + quad * 8];
#pragma unroll
            for (int nt = 0; nt < 4; ++nt) {
                bf16x8 vf = *(const bf16x8*)(vtb + (size_t)(nt * 16 + lrow) * Sc + k0 + ks * 32 + quad * 8);
#pragma unroll
                for (int mt = 0; mt < 2; ++mt)
                    oacc[mt][nt] = __builtin_amdgcn_mfma_f32_16x16x32_bf16(pf[mt], vf, oacc[mt][nt], 0, 0, 0);
            }
        }
    }
#pragma unroll
    for (int mt = 0; mt < 2; ++mt)
#pragma unroll
        for (int nt = 0; nt < 4; ++nt)
#pragma unroll
            for (int r = 0; r < 4; ++r) {
                int row = qb + wq + mt * 16 + quad * 4 + r;
                int dcol = nt * 16 + lrow;
                outp[((size_t)b * Sc + row) * Dc + h * 64 + dcol] = (bf16)(oacc[mt][nt][r] / l_i[mt][r]);
            }
}

__global__ __launch_bounds__(256) void gather_active(
    const float* __restrict__ qmem, const bf16* __restrict__ vbuf,
    float* __restrict__ xa, float* __restrict__ va)
{
    const int t = blockIdx.x;
    const int b = t >> 6;
    const int s = Sc - 64 + (t & 63);
    const float* qrow = qmem + ((size_t)(b * Sc + s)) * Dc;
    const bf16* vrow = vbuf + ((size_t)(b * Sc + s)) * Dc;
    for (int i = threadIdx.x; i < Dc; i += 256) {
        xa[(size_t)t * Dc + i] = qrow[i];
        va[(size_t)t * Dc + i] = (float)vrow[i];
    }
}

__global__ void wvec_kernel(const float* __restrict__ gamma,
                            float* __restrict__ wvec, float* __restrict__ wsum)
{
    const int t = threadIdx.x;
    const int b = t >> 6, si = t & 63;
    const int s = Sc - 64 + si;
    float v = gamma[b * Sc + s] * powf(0.95f, (float)(Sc - 1 - s));
    wvec[t] = v;
    __shared__ float red[128];
    red[t] = v; __syncthreads();
    for (int st = 64; st; st >>= 1) { if (t < st) red[t] += red[t + st]; __syncthreads(); }
    if (t == 0) wsum[0] = red[0];
}

__global__ __launch_bounds__(256) void phi2_f32(
    const float* __restrict__ z, float* __restrict__ feat)
{
    const int f = blockIdx.x * 256 + threadIdx.x;
    const int t = blockIdx.y;
    if (f >= FPOLY) return;
    const float* zr = z + (size_t)t * 64;
    float v;
    if (f < 64) v = zr[f];
    else { int i = (f - 64) >> 6, j = (f - 64) & 63; v = zr[i] * zr[j] * 0.125f; }
    feat[(size_t)t * FPOLY + f] = v;
}

__global__ __launch_bounds__(256) void phi2_bf16(
    const float* __restrict__ z, bf16* __restrict__ feat)
{
    const int f = blockIdx.x * 256 + threadIdx.x;
    const int t = blockIdx.y;
    if (f >= FPOLY) return;
    const float* zr = z + (size_t)t * 64;
    float v;
    if (f < 64) v = zr[f];
    else { int i = (f - 64) >> 6, j = (f - 64) & 63; v = zr[i] * zr[j] * 0.125f; }
    feat[(size_t)t * FPOLY + f] = (bf16)v;
}

__global__ void silu_kernel(const float* __restrict__ in, float* __restrict__ out, int n)
{
    int i = blockIdx.x * 256 + threadIdx.x;
    if (i < n) { float v = in[i]; out[i] = v / (1.f + expf(-v)); }
}

__global__ void dpred_kernel(const float* __restrict__ pred, const float* __restrict__ va,
                             const float* __restrict__ wvec, const float* __restrict__ wsum,
                             float* __restrict__ dpred)
{
    int i = blockIdx.x * 256 + threadIdx.x;
    if (i < NACT * Dc) {
        int t = i >> 10;
        dpred[i] = 2.f * wvec[t] / (wsum[0] + 1e-8f) * (pred[i] - va[i]);
    }
}

__global__ void dsilu_kernel(const float* __restrict__ dsu, const float* __restrict__ u,
                             float* __restrict__ du, int n)
{
    int i = blockIdx.x * 256 + threadIdx.x;
    if (i < n) {
        float uv = u[i];
        float sg = 1.f / (1.f + expf(-uv));
        du[i] = dsu[i] * sg * (1.f + uv * (1.f - sg));
    }
}

__global__ void dz_kernel(const float* __restrict__ dfeat, const float* __restrict__ za,
                          float* __restrict__ dz)
{
    const int t = blockIdx.x;
    const int k = threadIdx.x;
    const float* df = dfeat + (size_t)t * FPOLY;
    const float* z = za + (size_t)t * 64;
    float s1 = 0.f, s2 = 0.f;
    for (int j = 0; j < 64; ++j) {
        float zj = z[j];
        s1 += df[64 + k * 64 + j] * zj;
        s2 += df[64 + j * 64 + k] * zj;
    }
    dz[(size_t)t * 64 + k] = df[k] + 0.125f * (s1 + s2);
}

__global__ void sgate_kernel(const float* __restrict__ mg, float* __restrict__ out)
{
    out[0] = 1.f / (1.f + expf(-mg[0]));
}

__global__ void mulpad_kernel(bf16* __restrict__ a, const bf16* __restrict__ b)
{
    int i = blockIdx.x * 256 + threadIdx.x;
    if (i >= NTOK * FFNHP) return;
    int k = i % FFNHP;
    if (k >= FFNH) { a[i] = (bf16)0.f; return; }
    a[i] = (bf16)((float)a[i] * (float)b[i]);
}

// ---------------------------------------------------------------- launch
extern "C" void kernel_launch(void* const* d_in, const int* in_sizes, int n_in,
                              void* d_out, int out_size, void* d_ws, size_t ws_size,
                              hipStream_t stream)
{
    const float* x     = (const float*)d_in[0];
    const float* n1w   = (const float*)d_in[1];
    const float* n2w   = (const float*)d_in[2];
    const float* qkvw  = (const float*)d_in[3];
    const float* qnw   = (const float*)d_in[4];
    const float* knw   = (const float*)d_in[5];
    const float* gw1   = (const float*)d_in[6];
    const float* gw2   = (const float*)d_in[7];
    const float* mwk   = (const float*)d_in[8];
    const float* mw1   = (const float*)d_in[9];
    const float* mw2   = (const float*)d_in[10];
    const float* mgate = (const float*)d_in[11];
    const float* wow   = (const float*)d_in[12];
    const float* fw1   = (const float*)d_in[13];
    const float* fw2   = (const float*)d_in[14];
    const float* fw3   = (const float*)d_in[15];
    float* outp = (float*)d_out;

    char* base = (char*)d_ws;
    size_t off = 0;
    auto takeB = [&](size_t bytes) { char* p = base + off; off += (bytes + 255) & ~(size_t)255; return p; };

    // slabs (liveness-overlaid)
    char* slabA  = takeB(22544384);  // vt (16.8M) -> featC (17.0M) -> ff1b (22.5M)
    char* slabBC = takeB(16777216);  // qnb+knb -> x2 fp32
    char* slabD  = takeB(8388608);   // vb -> t1b
    char* slabE  = takeB(22544384);  // qmem fp32 (16.8M) -> ff3b (22.5M)
    char* slabF  = takeB(8388608);   // qtb -> attnb -> qmemb
    char* slabG  = takeB(17301504);  // hb (8.4M) -> mw1b (17.3M) -> h2b (8.4M)
    bf16* vt    = (bf16*)slabA;  bf16* featC = (bf16*)slabA;  bf16* ff1b = (bf16*)slabA;
    bf16* qnb = (bf16*)slabBC;   bf16* knb = (bf16*)(slabBC + 8388608);
    float* x2 = (float*)slabBC;
    bf16* vb = (bf16*)slabD;     bf16* t1b = (bf16*)slabD;
    float* qmem = (float*)slabE; bf16* ff3b = (bf16*)slabE;
    bf16* qtb = (bf16*)slabF;    bf16* attnb = (bf16*)slabF;  bf16* qmemb = (bf16*)slabF;
    bf16* hb = (bf16*)slabG;     bf16* mw1b = (bf16*)slabG;   bf16* h2b = (bf16*)slabG;

    // bf16 weights (transposed (N,K))
    bf16* qkvwT = (bf16*)takeB(6291456);
    bf16* gw1T  = (bf16*)takeB(262144);
    bf16* wowT  = (bf16*)takeB(2097152);
    bf16* mw1T  = (bf16*)takeB(17039360);
    bf16* mw2T  = (bf16*)takeB(4194304);
    bf16* fw1T  = (bf16*)takeB(5767168);
    bf16* fw3T  = (bf16*)takeB(5767168);
    bf16* fw2T  = (bf16*)takeB(5636096);
    bf16* mw2b  = (bf16*)takeB(4194304);   // straight copy (2048,1024)
    bf16* wkuTb = (bf16*)takeB(262144);    // (128 alloc, 1024)

    // fp32 misc
    float* zf    = (float*)takeB(1048576);
    float* gg1   = (float*)takeB(1048576);
    float* gamma = (float*)takeB(16384);
    float* wvec  = (float*)takeB(512);
    float* scal  = (float*)takeB(256);     // [0]=wsum [2]=sig(gate) [8..10]=invn
    float* psum  = (float*)takeB(131072);
    float* xa    = (float*)takeB(524288);
    float* va    = (float*)takeB(524288);
    float* za    = (float*)takeB(32768);
    float* featA = (float*)takeB(2129920);
    float* ua    = (float*)takeB(1048576);
    float* sua   = (float*)takeB(1048576);
    float* preda = (float*)takeB(524288);
    float* dpreda= (float*)takeB(524288);
    float* dsua  = (float*)takeB(1048576);
    float* dua   = (float*)takeB(1048576);
    float* dfeata= (float*)takeB(2129920);
    float* dza   = (float*)takeB(32768);
    float* SA    = (float*)takeB(196608);  // 3 x 128x128
    float* CA    = (float*)takeB(196608);
    float* MA    = (float*)takeB(196608);
    float* FA    = (float*)takeB(196608);
    float* FcA   = (float*)takeB(196608);
    float* FcB   = (float*)takeB(196608);
    float* ZA    = (float*)takeB(196608);
    float* PT1   = (float*)takeB(1048576);
    float* PT2   = (float*)takeB(524288);
    float* PT3   = (float*)takeB(32768);
    float* wku   = (float*)takeB(262144);
    // bf16 misc
    bf16* featAb = (bf16*)takeB(1064960);
    bf16* suab   = (bf16*)takeB(524288);
    bf16* xab    = (bf16*)takeB(262144);
    bf16* duab   = (bf16*)takeB(524288);
    bf16* dpredab= (bf16*)takeB(262144);
    bf16* dzab   = (bf16*)takeB(16384);
    bf16* PT1Tb  = (bf16*)takeB(524288);
    bf16* PT2Tb  = (bf16*)takeB(262144);
    bf16* tBb    = (bf16*)takeB(524288);

    auto gemmF = [&](int TA, int TB, const float* A, const float* B, const float* Cin, float* C,
                     int M, int N, int K, int lda, int ldb, int ldc,
                     float alpha, float beta, int act, const float* sA) {
        dim3 grid((N + 63) / 64, (M + 63) / 64);
        if (!TA && !TB)      gemm_f32<0, 0><<<grid, 256, 0, stream>>>(A, B, Cin, C, M, N, K, lda, ldb, ldc, alpha, beta, act, sA);
        else if (!TA && TB)  gemm_f32<0, 1><<<grid, 256, 0, stream>>>(A, B, Cin, C, M, N, K, lda, ldb, ldc, alpha, beta, act, sA);
        else if (TA && !TB)  gemm_f32<1, 0><<<grid, 256, 0, stream>>>(A, B, Cin, C, M, N, K, lda, ldb, ldc, alpha, beta, act, sA);
        else                 gemm_f32<1, 1><<<grid, 256, 0, stream>>>(A, B, Cin, C, M, N, K, lda, ldb, ldc, alpha, beta, act, sA);
    };
    auto gemmB = [&](int outbf, int cinbf, const bf16* A, const bf16* Bt,
                     const void* Cin, void* C, int M, int N, int K, int ldc,
                     float alpha, float beta, int act, const float* sptr) {
        dim3 grid((N + 127) / 128, M / 128);
        if (outbf && cinbf) gemm_bt<1, 1><<<grid, 256, 0, stream>>>(A, Bt, Cin, C, M, N, K, ldc, alpha, beta, act, sptr);
        else if (outbf)     gemm_bt<1, 0><<<grid, 256, 0, stream>>>(A, Bt, Cin, C, M, N, K, ldc, alpha, beta, act, sptr);
        else                gemm_bt<0, 0><<<grid, 256, 0, stream>>>(A, Bt, Cin, C, M, N, K, ldc, alpha, beta, act, sptr);
    };
    auto tconv = [&](const float* W, bf16* Wt, int K, int N, int Kpad) {
        tconv_kernel<<<dim3((Kpad + 31) / 32, (N + 31) / 32), 256, 0, stream>>>(W, Wt, K, N, Kpad);
    };

    // 0. weight converts
    tconv(qkvw, qkvwT, Dc, 3 * Dc, Dc);
    tconv(gw1, gw1T, Dc, GGH, Dc);
    tconv(wow, wowT, Dc, Dc, Dc);
    tconv(mw1, mw1T, FPOLY, MHID, FPOLY);
    tconv(mw2, mw2T, MHID, Dc, MHID);
    tconv(fw1, fw1T, Dc, FFNH, Dc);
    tconv(fw3, fw3T, Dc, FFNH, Dc);
    tconv(fw2, fw2T, FFNH, Dc, FFNHP);
    cvt_kernel<<<2048, 256, 0, stream>>>(mw2, mw2b, MHID * Dc);
    sgate_kernel<<<1, 1, 0, stream>>>(mgate, scal + 2);

    // 1-2. rmsnorm, q/k/v, gamma
    rms_rows<<<NTOK, 256, 0, stream>>>(x, n1w, hb, Dc);
    gemmB(1, 0, hb, qkvwT,          nullptr, qtb, NTOK, Dc, Dc, Dc, 1.f, 0.f, 0, nullptr);
    snr_one<<<dim3(Sc / 4, Hc, Bc), 256, 0, stream>>>(qtb, qnw, qnb);
    gemmB(1, 0, hb, qkvwT + (size_t)1024 * Dc, nullptr, qtb, NTOK, Dc, Dc, Dc, 1.f, 0.f, 0, nullptr);
    snr_one<<<dim3(Sc / 4, Hc, Bc), 256, 0, stream>>>(qtb, knw, knb);
    gemmB(1, 0, hb, qkvwT + (size_t)2048 * Dc, nullptr, vb, NTOK, Dc, Dc, Dc, 1.f, 0.f, 0, nullptr);
    gemmB(0, 0, hb, gw1T, nullptr, gg1, NTOK, GGH, Dc, GGH, 1.f, 0.f, 0, nullptr);
    gamma_kernel<<<NTOK / 4, 256, 0, stream>>>(gg1, gw2, gamma);
    // hb dead -> mw1b overlay legal
    cvt_kernel<<<2048, 256, 0, stream>>>(mw1, mw1b, FPOLY * MHID);

    // 3. V transpose (vt in slabA), q_mem, attention
    vtrans_kernel<<<dim3(Sc / 32, 2, Bc * Hc), 256, 0, stream>>>(vb, vt);
    kpsum_kernel<<<dim3(Bc * Hc, 16), 64, 0, stream>>>(knb, psum);
    qmem2_kernel<<<dim3(Bc * Hc, 16), 64, 0, stream>>>(qnb, knb, gamma, psum, qmem);
    attn_mfma<<<dim3(Sc / 128, Hc, Bc), 256, 0, stream>>>(qnb, knb, vt, attnb);

    // 4. actives
    gather_active<<<NACT, 256, 0, stream>>>(qmem, vb, xa, va);
    wvec_kernel<<<1, 128, 0, stream>>>(gamma, wvec, scal);
    cvt_kernel<<<256, 256, 0, stream>>>(xa, xab, NACT * Dc);

    // 5. gradient chain (128 active tokens)
    gemmF(0, 0, xa, mwk, nullptr, za, NACT, HDc, Dc, Dc, HDc, HDc, 1.f, 0.f, 0, nullptr);
    phi2_f32<<<dim3((FPOLY + 255) / 256, NACT), 256, 0, stream>>>(za, featA);
    cvt_kernel<<<520, 256, 0, stream>>>(featA, featAb, NACT * FPOLY);
    gemmB(0, 0, featAb, mw1T, nullptr, ua, NACT, MHID, FPOLY, MHID, 1.f, 0.f, 0, nullptr);
    silu_kernel<<<(NACT * MHID + 255) / 256, 256, 0, stream>>>(ua, sua, NACT * MHID);
    cvt_kernel<<<256, 256, 0, stream>>>(sua, suab, NACT * MHID);
    gemmB(0, 0, suab, mw2T, nullptr, preda, NACT, Dc, MHID, Dc, 1.f, 0.f, 0, nullptr);
    dpred_kernel<<<(NACT * Dc + 255) / 256, 256, 0, stream>>>(preda, va, wvec, scal, dpreda);
    cvt_kernel<<<256, 256, 0, stream>>>(dpreda, dpredab, NACT * Dc);
    gemmB(0, 0, dpredab, mw2b, nullptr, dsua, NACT, MHID, Dc, MHID, 1.f, 0.f, 0, nullptr);
    dsilu_kernel<<<(NACT * MHID + 255) / 256, 256, 0, stream>>>(dsua, ua, dua, NACT * MHID);
    cvt_kernel<<<256, 256, 0, stream>>>(dua, duab, NACT * MHID);
    gemmB(0, 0, duab, mw1b, nullptr, dfeata, NACT, FPOLY, MHID, FPOLY, 1.f, 0.f, 0, nullptr);
    dz_kernel<<<NACT, 64, 0, stream>>>(dfeata, za, dza);
    cvt_kernel<<<32, 256, 0, stream>>>(dza, dzab, NACT * HDc);

    // 6. Newton-Schulz in 128x128 space (batched over the 3 runs)
    //    S=QQ^T, C0=PT PT^T/||G||^2; iterate M=S@C, F=aI+bM+cM^2, Fc=Fc@F, C=F^T(C@F)
    gemmB(0, 0, featAb, featAb, nullptr, SA,          128, 128, FPOLY, 128, 1.f, 0.f, 0, nullptr);
    gemmB(0, 0, suab,   suab,   nullptr, SA + 16384,  128, 128, MHID,  128, 1.f, 0.f, 0, nullptr);
    gemmB(0, 0, xab,    xab,    nullptr, SA + 32768,  128, 128, Dc,    128, 1.f, 0.f, 0, nullptr);
    gemmB(0, 0, duab,   duab,   nullptr, CA,          128, 128, MHID,  128, 1.f, 0.f, 0, nullptr);
    gemmB(0, 0, dpredab,dpredab,nullptr, CA + 16384,  128, 128, Dc,    128, 1.f, 0.f, 0, nullptr);
    gemmB(0, 0, dzab,   dzab,   nullptr, CA + 32768,  128, 128, HDc,   128, 1.f, 0.f, 0, nullptr);
    ns_norm_kernel<<<3, 256, 0, stream>>>(SA, CA, scal + 8);
    {
        dim3 g3(2, 2, 3);
        float* fcs[2] = {FcB, FcA};
        for (int t = 0; t < 5; ++t) {
            b128mm<0><<<g3, 256, 0, stream>>>(SA, CA, nullptr, MA, 1.f, 0.f, 0.f);
            b128mm<0><<<g3, 256, 0, stream>>>(MA, MA, MA, FA, 2.0315f, -4.775f, 3.4445f);
            if (t == 0)
                hipMemcpyAsync(FcB, FA, 3 * 16384 * sizeof(float), hipMemcpyDeviceToDevice, stream);
            else
                b128mm<0><<<g3, 256, 0, stream>>>(fcs[t & 1], FA, nullptr, fcs[1 - (t & 1)], 1.f, 0.f, 0.f);
            if (t < 4) {
                b128mm<0><<<g3, 256, 0, stream>>>(CA, FA, nullptr, ZA, 1.f, 0.f, 0.f);
                b128mm<1><<<g3, 256, 0, stream>>>(FA, ZA, nullptr, CA, 1.f, 0.f, 0.f);
            }
        }
    }
    // PT5 = invn * Fc^T @ PTraw   (final Fc lives in FcB)
    gemmF(1, 0, FcB,         dua,    nullptr, PT1, 128, MHID, 128, 128, MHID, MHID, 1.f, 0.f, 0, scal + 8);
    gemmF(1, 0, FcB + 16384, dpreda, nullptr, PT2, 128, Dc,   128, 128, Dc,   Dc,   1.f, 0.f, 0, scal + 9);
    gemmF(1, 0, FcB + 32768, dza,    nullptr, PT3, 128, HDc,  128, 128, HDc,  HDc,  1.f, 0.f, 0, scal + 10);
    tconv(PT1, PT1Tb, 128, MHID, 128);
    tconv(PT2, PT2Tb, 128, Dc, 128);
    gemmF(1, 0, xa, PT3, mwk, wku, Dc, HDc, 128, Dc, HDc, HDc, -0.01f, 0.999f, 0, nullptr);
    tconv(wku, wkuTb, Dc, HDc, Dc);

    // 7. x2 = x + attn@wo (attnb dies); then qmemb overlay in slabF
    gemmB(0, 0, attnb, wowT, x, x2, NTOK, Dc, Dc, Dc, 1.f, 1.f, 0, nullptr);
    cvt_kernel<<<2048, 256, 0, stream>>>(qmem, qmemb, NTOK * Dc);
    gemmB(0, 0, qmemb, wkuTb, nullptr, zf, NTOK, HDc, Dc, HDc, 1.f, 0.f, 0, nullptr);

    // 8. memory forward (low-rank updated weights), 2 chunks
    for (int c = 0; c < NTOK / MCH; ++c) {
        const int R = c * MCH;
        phi2_bf16<<<dim3((FPOLY + 255) / 256, MCH), 256, 0, stream>>>(zf + (size_t)R * HDc, featC);
        gemmB(1, 0, featC, mw1T, nullptr, t1b, MCH, MHID, FPOLY, MHID, 0.999f, 0.f, 0, nullptr);
        gemmB(1, 0, featC, featAb, nullptr, tBb, MCH, NACT, FPOLY, NACT, 1.f, 0.f, 0, nullptr);
        gemmB(1, 1, tBb, PT1Tb, t1b, t1b, MCH, MHID, NACT, MHID, -0.01f, 1.f, 1, nullptr);
        gemmB(0, 0, t1b, mw2T, x2 + (size_t)R * Dc, x2 + (size_t)R * Dc,
              MCH, Dc, MHID, Dc, 0.999f, 1.f, 0, scal + 2);
        gemmB(1, 0, t1b, suab, nullptr, tBb, MCH, NACT, MHID, NACT, 1.f, 0.f, 0, nullptr);
        gemmB(0, 0, tBb, PT2Tb, x2 + (size_t)R * Dc, x2 + (size_t)R * Dc,
              MCH, Dc, NACT, Dc, -0.01f, 1.f, 0, scal + 2);
    }
    // 9. FFN (swiglu)
    rms_rows<<<NTOK, 256, 0, stream>>>(x2, n2w, h2b, Dc);
    gemmB(1, 0, h2b, fw1T, nullptr, ff1b, NTOK, FFNH, Dc, FFNHP, 1.f, 0.f, 1, nullptr);
    gemmB(1, 0, h2b, fw3T, nullptr, ff3b, NTOK, FFNH, Dc, FFNHP, 1.f, 0.f, 0, nullptr);
    mulpad_kernel<<<(NTOK * FFNHP + 255) / 256, 256, 0, stream>>>(ff1b, ff3b);
    gemmB(0, 0, ff1b, fw2T, x2, outp, NTOK, Dc, FFNHP, Dc, 1.f, 1.f, 0, nullptr);
}